// Round 1
// baseline (1771.169 us; speedup 1.0000x reference)
//
#include <hip/hip_runtime.h>
#include <math.h>

// ---------------------------------------------------------------------------
// SRModel: encoder convs -> bicubic up -> per-pixel kernel-MLP -> dynamic
// 7x7 weighted sum -> grouped refiner convs -> color-preserving fusion.
// Round 1: correctness-first fp32 implementation.
// ---------------------------------------------------------------------------

#define HL 80
#define WL 80
#define HH 320
#define WH 320
#define NPIX (HH*WH)      // 102400
#define LRPIX (HL*WL)     // 6400
#define FEAT 64
#define HID 256
#define IN_DIM 106
#define HEADS 4
#define K2 49

__device__ __forceinline__ float gelu_f(float x) {
  // jax.nn.gelu default approximate=True (tanh form)
  float x3 = x*x*x;
  float t = tanhf(0.7978845608028654f*(x + 0.044715f*x3));
  return 0.5f*x*(1.0f+t);
}

__device__ __forceinline__ float keys_cubic(float x) {
  // Keys cubic, a = -0.5 (jax _fill_keys_cubic_kernel)
  x = fabsf(x);
  if (x >= 2.0f) return 0.0f;
  if (x >= 1.0f) return ((-0.5f*x + 2.5f)*x - 4.0f)*x + 2.0f;
  return ((1.5f*x - 2.5f)*x)*x + 1.0f;
}

// ---------------- encoder conv3x3 + GELU (SAME, zero pad) -------------------
// 64 out channels, thread = (pixel, chunk of 8 oc). grid covers 6400*8 threads.
__global__ void enc_conv(const float* __restrict__ in, const float* __restrict__ w,
                         const float* __restrict__ bias, float* __restrict__ out,
                         int IC) {
  int id = blockIdx.x*blockDim.x + threadIdx.x;
  if (id >= LRPIX*8) return;
  int pix = id % LRPIX;
  int chunk = id / LRPIX;        // uniform per block (6400 = 25 blocks * 256)
  int y = pix / WL, x = pix % WL;
  float acc[8];
#pragma unroll
  for (int o=0;o<8;o++) acc[o] = bias[chunk*8+o];
  for (int ic=0; ic<IC; ic++) {
    const float* ip = in + ic*LRPIX;
    const float* wp = w + (chunk*8*IC + ic)*9;
#pragma unroll
    for (int ky=0; ky<3; ky++) {
      int yy = y+ky-1;
      if (yy < 0 || yy >= HL) continue;
#pragma unroll
      for (int kx=0; kx<3; kx++) {
        int xx = x+kx-1;
        if (xx < 0 || xx >= WL) continue;
        float v = ip[yy*WL+xx];
#pragma unroll
        for (int o=0;o<8;o++)
          acc[o] += v * wp[o*IC*9 + ky*3+kx];
      }
    }
  }
#pragma unroll
  for (int o=0;o<8;o++)
    out[(chunk*8+o)*LRPIX + pix] = gelu_f(acc[o]);
}

// ---------------- bicubic upsample (matches jax.image.resize 'cubic') ------
__global__ void bicubic_up(const float* __restrict__ lr, float* __restrict__ up) {
  int id = blockIdx.x*blockDim.x + threadIdx.x;
  if (id >= 3*NPIX) return;
  int c = id / NPIX, p = id % NPIX;
  int hy = p / WH, hx = p % WH;
  float sx = (hx+0.5f)*0.25f - 0.5f;
  float sy = (hy+0.5f)*0.25f - 0.5f;
  int bx = (int)floorf(sx), by = (int)floorf(sy);
  float wx[4], wy[4];
  int ix[4], iy[4];
  float sumx = 0.f, sumy = 0.f;
#pragma unroll
  for (int i=0;i<4;i++) {
    int j = bx-1+i;
    float wv = (j>=0 && j<WL) ? keys_cubic(sx - (float)j) : 0.f;
    wx[i] = wv; ix[i] = min(max(j,0), WL-1); sumx += wv;
    j = by-1+i;
    wv = (j>=0 && j<HL) ? keys_cubic(sy - (float)j) : 0.f;
    wy[i] = wv; iy[i] = min(max(j,0), HL-1); sumy += wv;
  }
  float inx = 1.f/sumx, iny = 1.f/sumy;   // border renorm (interior sums to 1)
  const float* src = lr + c*LRPIX;
  float acc = 0.f;
#pragma unroll
  for (int i=0;i<4;i++) {
    float rowv = 0.f;
#pragma unroll
    for (int j=0;j<4;j++) rowv += wx[j]*src[iy[i]*WL + ix[j]];
    acc += wy[i]*rowv;
  }
  up[c*NPIX + p] = acc * inx * iny;
}

// ---------------- fused per-pixel MLP + softmax kernels + 7x7 sum ----------
// Block: 512 threads (8 waves), 64 pixels. Wave w owns pixels w*8..w*8+7;
// lane t owns output neurons 4t..4t+3. Weights staged in 64-row LDS tiles.
#define PMT 512
__global__ __launch_bounds__(PMT)
void pixel_mlp(const float* __restrict__ f, const float* __restrict__ lr,
               const float* __restrict__ w0, const float* __restrict__ b0,
               const float* __restrict__ wh, const float* __restrict__ bh,
               const float* __restrict__ kw, const float* __restrict__ kb,
               const float* __restrict__ gw, const float* __restrict__ gb,
               float* __restrict__ res0) {
  __shared__ float xbuf[64*108];    // 27.0 KB (stride 108)
  __shared__ float hbuf[64*256];    // 64 KB
  __shared__ float wtile[64*256];   // 64 KB (reused as kbuf [64][205])
  int tid = threadIdx.x;
  int wave = tid >> 6, lane = tid & 63;
  int n0 = blockIdx.x * 64;

  // ---- Phase A: build x = [cfeat(64) | PE(40) | fx fy] per pixel ----
  for (int idx = tid; idx < 64*IN_DIM; idx += PMT) {
    int p = idx / IN_DIM, k = idx - p*IN_DIM;
    int n = n0 + p;
    int hy = n / WH, hx = n % WH;
    float v;
    if (k < 64) {
      float lx = (hx+0.5f)*0.25f - 0.5f;
      float ly = (hy+0.5f)*0.25f - 0.5f;
      int bxi = min(max((int)floorf(lx),0), WL-1);
      int byi = min(max((int)floorf(ly),0), HL-1);
      v = f[k*LRPIX + byi*WL + bxi];
    } else if (k < 104) {
      int band = (k-64) >> 2, r = (k-64) & 3;
      float freq = (float)(1<<band) * 3.14159265358979323846f;
      float hxn = (hx+0.5f)*(2.0f/WH) - 1.0f;
      float hyn = (hy+0.5f)*(2.0f/HH) - 1.0f;
      float arg = ((r<2) ? hxn : hyn) * freq;
      v = (r&1) ? cosf(arg) : sinf(arg);
    } else {
      float lx = (hx+0.5f)*0.25f - 0.5f;
      float ly = (hy+0.5f)*0.25f - 0.5f;
      v = (k==104) ? (lx - floorf(lx)) : (ly - floorf(ly));
    }
    xbuf[p*108 + k] = v;
  }
  __syncthreads();

  float acc[8][4];
  // ---- layer 0: x[106] @ w0[106][256] ----
#pragma unroll
  for (int p=0;p<8;p++) { acc[p][0]=0.f;acc[p][1]=0.f;acc[p][2]=0.f;acc[p][3]=0.f; }
  for (int kt=0; kt<IN_DIM; kt+=64) {
    int rows = min(64, IN_DIM-kt);
    for (int idx = tid; idx < rows*64; idx += PMT)
      ((float4*)wtile)[idx] = ((const float4*)(w0 + kt*HID))[idx];
    __syncthreads();
    for (int kk=0; kk<rows; kk++) {
      float4 wv = *(const float4*)&wtile[kk*HID + lane*4];
#pragma unroll
      for (int p=0;p<8;p++) {
        float hv = xbuf[(wave*8+p)*108 + kt+kk];   // wave-uniform broadcast
        acc[p][0] += hv*wv.x; acc[p][1] += hv*wv.y;
        acc[p][2] += hv*wv.z; acc[p][3] += hv*wv.w;
      }
    }
    __syncthreads();
  }
  {
    float4 bb = *(const float4*)&b0[lane*4];
#pragma unroll
    for (int p=0;p<8;p++) {
      float4 hv;
      hv.x = gelu_f(acc[p][0]+bb.x);
      hv.y = gelu_f(acc[p][1]+bb.y);
      hv.z = gelu_f(acc[p][2]+bb.z);
      hv.w = gelu_f(acc[p][3]+bb.w);
      *(float4*)&hbuf[(wave*8+p)*HID + lane*4] = hv;
    }
  }
  __syncthreads();

  // ---- 4 hidden layers: h[256] @ wh[256][256] ----
  for (int L=0; L<4; L++) {
    const float* W = wh + L*HID*HID;
#pragma unroll
    for (int p=0;p<8;p++) { acc[p][0]=0.f;acc[p][1]=0.f;acc[p][2]=0.f;acc[p][3]=0.f; }
    for (int kt=0; kt<HID; kt+=64) {
      for (int idx = tid; idx < 64*64; idx += PMT)
        ((float4*)wtile)[idx] = ((const float4*)(W + kt*HID))[idx];
      __syncthreads();
      for (int kk=0; kk<64; kk++) {
        float4 wv = *(const float4*)&wtile[kk*HID + lane*4];
#pragma unroll
        for (int p=0;p<8;p++) {
          float hv = hbuf[(wave*8+p)*HID + kt+kk];
          acc[p][0] += hv*wv.x; acc[p][1] += hv*wv.y;
          acc[p][2] += hv*wv.z; acc[p][3] += hv*wv.w;
        }
      }
      __syncthreads();
    }
    float4 bb = *(const float4*)&bh[L*HID + lane*4];
#pragma unroll
    for (int p=0;p<8;p++) {
      float4 hv;
      hv.x = gelu_f(acc[p][0]+bb.x);
      hv.y = gelu_f(acc[p][1]+bb.y);
      hv.z = gelu_f(acc[p][2]+bb.z);
      hv.w = gelu_f(acc[p][3]+bb.w);
      *(float4*)&hbuf[(wave*8+p)*HID + lane*4] = hv;
    }
    __syncthreads();
  }

  // ---- kern (196) + gate (4) heads, combined 200 columns ----
  float acc2[8][4];
#pragma unroll
  for (int p=0;p<8;p++) { acc2[p][0]=0.f;acc2[p][1]=0.f;acc2[p][2]=0.f;acc2[p][3]=0.f; }
  for (int kt=0; kt<HID; kt+=64) {
    for (int idx = tid; idx < 64*200; idx += PMT) {
      int kk = idx / 200, j = idx - kk*200;
      wtile[kk*200 + j] = (j<196) ? kw[(kt+kk)*196 + j] : gw[(kt+kk)*4 + (j-196)];
    }
    __syncthreads();
    if (lane < 50) {
      for (int kk=0; kk<64; kk++) {
        float4 wv = *(const float4*)&wtile[kk*200 + lane*4];
#pragma unroll
        for (int p=0;p<8;p++) {
          float hv = hbuf[(wave*8+p)*HID + kt+kk];
          acc2[p][0] += hv*wv.x; acc2[p][1] += hv*wv.y;
          acc2[p][2] += hv*wv.z; acc2[p][3] += hv*wv.w;
        }
      }
    }
    __syncthreads();
  }
  float* kbuf = wtile;   // reuse: [64][205] (205 = odd stride, conflict-free)
  if (lane < 50) {
#pragma unroll
    for (int u=0;u<4;u++) {
      int j = lane*4+u;
      float bias = (j<196) ? kb[j] : gb[j-196];
#pragma unroll
      for (int p=0;p<8;p++)
        kbuf[(wave*8+p)*205 + j] = acc2[p][u] + bias;
    }
  }
  __syncthreads();

  // ---- Phase E: per-pixel softmaxes + gated 7x7 weighted sum ----
  if (tid < 64) {
    int p = tid;
    int n = n0 + p;
    int hy = n / WH, hx = n % WH;
    float lx = (hx+0.5f)*0.25f - 0.5f;
    float ly = (hy+0.5f)*0.25f - 0.5f;
    int bxi = min(max((int)floorf(lx),0), WL-1);
    int byi = min(max((int)floorf(ly),0), HL-1);
    const float* kp = &kbuf[p*205];
    // gate softmax (tau = 1)
    float g0=kp[196], g1=kp[197], g2=kp[198], g3=kp[199];
    float gm = fmaxf(fmaxf(g0,g1), fmaxf(g2,g3));
    g0=expf(g0-gm); g1=expf(g1-gm); g2=expf(g2-gm); g3=expf(g3-gm);
    float gs = 1.0f/(g0+g1+g2+g3);
    float m[4], s[4], gos[4];
#pragma unroll
    for (int h=0; h<4; h++) {
      float mh = -1e30f;
      for (int q=0;q<K2;q++) mh = fmaxf(mh, kp[h*K2+q]);
      float sh = 0.f;
      for (int q=0;q<K2;q++) sh += expf(kp[h*K2+q]-mh);
      m[h]=mh; s[h]=sh;
    }
    gos[0]=g0*gs/s[0]; gos[1]=g1*gs/s[1]; gos[2]=g2*gs/s[2]; gos[3]=g3*gs/s[3];
    float r0=0.f,r1=0.f,r2=0.f;
    for (int q=0;q<K2;q++) {
      int dy = q/7 - 3, dx = q%7 - 3;
      int ny = min(max(byi+dy,0),HL-1);
      int nx = min(max(bxi+dx,0),WL-1);
      float wq = gos[0]*expf(kp[q]-m[0]) + gos[1]*expf(kp[K2+q]-m[1])
               + gos[2]*expf(kp[2*K2+q]-m[2]) + gos[3]*expf(kp[3*K2+q]-m[3]);
      int o = ny*WL + nx;
      r0 += wq*lr[o]; r1 += wq*lr[LRPIX+o]; r2 += wq*lr[2*LRPIX+o];
    }
    res0[n] = r0; res0[NPIX+n] = r1; res0[2*NPIX+n] = r2;
  }
}

// ---------------- refiner conv0: groups=3, 2ch -> 16ch, GELU ----------------
__global__ void rconv0(const float* __restrict__ lrup, const float* __restrict__ res0,
                       const float* __restrict__ w, const float* __restrict__ bias,
                       float* __restrict__ out) {
  int id = blockIdx.x*blockDim.x + threadIdx.x;
  if (id >= 3*NPIX) return;
  int g = id / NPIX, p = id % NPIX;   // g uniform per block (102400 = 400*256)
  int y = p / WH, x = p % WH;
  float acc[16];
#pragma unroll
  for (int o=0;o<16;o++) acc[o] = bias[g*16+o];
#pragma unroll
  for (int ic=0; ic<2; ic++) {
    const float* src = (ic==0 ? lrup : res0) + g*NPIX;
#pragma unroll
    for (int ky=0;ky<3;ky++) {
      int yy = y+ky-1;
      if (yy<0||yy>=HH) continue;
#pragma unroll
      for (int kx=0;kx<3;kx++) {
        int xx = x+kx-1;
        if (xx<0||xx>=WH) continue;
        float v = src[yy*WH+xx];
#pragma unroll
        for (int o=0;o<16;o++)
          acc[o] += v * w[((g*16+o)*2+ic)*9 + ky*3+kx];
      }
    }
  }
#pragma unroll
  for (int o=0;o<16;o++)
    out[(g*16+o)*NPIX + p] = gelu_f(acc[o]);
}

// ---------------- refiner conv1: groups=3, 16ch -> 16ch, GELU ---------------
__global__ void rconv1(const float* __restrict__ hr0, const float* __restrict__ w,
                       const float* __restrict__ bias, float* __restrict__ out) {
  int id = blockIdx.x*blockDim.x + threadIdx.x;
  if (id >= 3*NPIX) return;
  int g = id / NPIX, p = id % NPIX;
  int y = p / WH, x = p % WH;
  float acc[16];
#pragma unroll
  for (int o=0;o<16;o++) acc[o] = bias[g*16+o];
  for (int ic=0; ic<16; ic++) {
    const float* src = hr0 + (g*16+ic)*NPIX;
#pragma unroll
    for (int ky=0;ky<3;ky++) {
      int yy = y+ky-1;
      if (yy<0||yy>=HH) continue;
#pragma unroll
      for (int kx=0;kx<3;kx++) {
        int xx = x+kx-1;
        if (xx<0||xx>=WH) continue;
        float v = src[yy*WH+xx];
#pragma unroll
        for (int o=0;o<16;o++)
          acc[o] += v * w[((g*16+o)*16+ic)*9 + ky*3+kx];
      }
    }
  }
#pragma unroll
  for (int o=0;o<16;o++)
    out[(g*16+o)*NPIX + p] = gelu_f(acc[o]);
}

// --------- refiner conv2 (16->1 per group) + sr + gray fusion + clip --------
__global__ void rconv2_fuse(const float* __restrict__ hr1, const float* __restrict__ lrup,
                            const float* __restrict__ res0, const float* __restrict__ w,
                            const float* __restrict__ bias, float* __restrict__ out) {
  int p = blockIdx.x*blockDim.x + threadIdx.x;
  if (p >= NPIX) return;
  int y = p / WH, x = p % WH;
  float sr[3], lu[3];
#pragma unroll
  for (int c=0;c<3;c++) {
    float acc = bias[c];
    for (int ic=0; ic<16; ic++) {
      const float* src = hr1 + (c*16+ic)*NPIX;
#pragma unroll
      for (int ky=0;ky<3;ky++) {
        int yy=y+ky-1; if (yy<0||yy>=HH) continue;
#pragma unroll
        for (int kx=0;kx<3;kx++) {
          int xx=x+kx-1; if (xx<0||xx>=WH) continue;
          acc += src[yy*WH+xx] * w[(c*16+ic)*9 + ky*3+kx];
        }
      }
    }
    float l = lrup[c*NPIX+p];
    lu[c]=l;
    float srv = l + res0[c*NPIX+p] + acc;
    sr[c] = fminf(fmaxf(srv,0.f),1.f);
  }
  float delta = 0.2989f*(sr[0]-lu[0]) + 0.587f*(sr[1]-lu[1]) + 0.114f*(sr[2]-lu[2]);
#pragma unroll
  for (int c=0;c<3;c++)
    out[c*NPIX+p] = fminf(fmaxf(lu[c]+delta,0.f),1.f);
}

// ---------------------------------------------------------------------------
extern "C" void kernel_launch(void* const* d_in, const int* in_sizes, int n_in,
                              void* d_out, int out_size, void* d_ws, size_t ws_size,
                              hipStream_t stream) {
  const float* lr     = (const float*)d_in[0];
  const float* enc_w0 = (const float*)d_in[1];
  const float* enc_b0 = (const float*)d_in[2];
  const float* enc_wh = (const float*)d_in[3];
  const float* enc_bh = (const float*)d_in[4];
  const float* mlp_w0 = (const float*)d_in[5];
  const float* mlp_b0 = (const float*)d_in[6];
  const float* mlp_wh = (const float*)d_in[7];
  const float* mlp_bh = (const float*)d_in[8];
  const float* kern_w = (const float*)d_in[9];
  const float* kern_b = (const float*)d_in[10];
  const float* gate_w = (const float*)d_in[11];
  const float* gate_b = (const float*)d_in[12];
  const float* ref_w0 = (const float*)d_in[13];
  const float* ref_b0 = (const float*)d_in[14];
  const float* ref_w1 = (const float*)d_in[15];
  const float* ref_b1 = (const float*)d_in[16];
  const float* ref_w2 = (const float*)d_in[17];
  const float* ref_b2 = (const float*)d_in[18];
  float* out = (float*)d_out;
  float* ws = (float*)d_ws;

  float* f_a  = ws;                 // 409600 floats
  float* f_b  = ws + 409600;        // 409600
  float* lrup = ws + 819200;        // 307200
  float* res0 = ws + 1126400;       // 307200
  float* hr0  = ws + 1433600;       // 4915200
  float* hr1  = ws + 6348800;       // 4915200  (total ~45 MB)

  // encoder: 3->64 then 3x (64->64), ping-pong f_a/f_b
  enc_conv<<<200, 256, 0, stream>>>(lr, enc_w0, enc_b0, f_a, 3);
  enc_conv<<<200, 256, 0, stream>>>(f_a, enc_wh + 0*36864, enc_bh + 0,   f_b, 64);
  enc_conv<<<200, 256, 0, stream>>>(f_b, enc_wh + 1*36864, enc_bh + 64,  f_a, 64);
  enc_conv<<<200, 256, 0, stream>>>(f_a, enc_wh + 2*36864, enc_bh + 128, f_b, 64);

  bicubic_up<<<1200, 256, 0, stream>>>(lr, lrup);

  pixel_mlp<<<1600, PMT, 0, stream>>>(f_b, lr, mlp_w0, mlp_b0, mlp_wh, mlp_bh,
                                      kern_w, kern_b, gate_w, gate_b, res0);

  rconv0<<<1200, 256, 0, stream>>>(lrup, res0, ref_w0, ref_b0, hr0);
  rconv1<<<1200, 256, 0, stream>>>(hr0, ref_w1, ref_b1, hr1);
  rconv2_fuse<<<400, 256, 0, stream>>>(hr1, lrup, res0, ref_w2, ref_b2, out);
}

// Round 2
// 765.258 us; speedup vs baseline: 2.3145x; 2.3145x over previous
//
#include <hip/hip_runtime.h>
#include <math.h>

// ---------------------------------------------------------------------------
// SRModel. Round 2: pixel MLP on fp16 MFMA (16x16x32), weights pre-transposed
// to n-major fp16; activations in XOR-swizzled LDS; parallel softmax phase.
// ---------------------------------------------------------------------------

#define HL 80
#define WL 80
#define HH 320
#define WH 320
#define NPIX (HH*WH)      // 102400
#define LRPIX (HL*WL)     // 6400
#define HID 256
#define K2 49

typedef _Float16 half8 __attribute__((ext_vector_type(8)));
typedef float f32x4 __attribute__((ext_vector_type(4)));

__device__ __forceinline__ float gelu_f(float x) {
  // jax.nn.gelu default approximate=True (tanh form)
  float x3 = x*x*x;
  float t = tanhf(0.7978845608028654f*(x + 0.044715f*x3));
  return 0.5f*x*(1.0f+t);
}

__device__ __forceinline__ float keys_cubic(float x) {
  x = fabsf(x);
  if (x >= 2.0f) return 0.0f;
  if (x >= 1.0f) return ((-0.5f*x + 2.5f)*x - 4.0f)*x + 2.0f;
  return ((1.5f*x - 2.5f)*x)*x + 1.0f;
}

// ---------------- encoder conv3x3 + GELU (SAME, zero pad) -------------------
__global__ void enc_conv(const float* __restrict__ in, const float* __restrict__ w,
                         const float* __restrict__ bias, float* __restrict__ out,
                         int IC) {
  int id = blockIdx.x*blockDim.x + threadIdx.x;
  if (id >= LRPIX*8) return;
  int pix = id % LRPIX;
  int chunk = id / LRPIX;
  int y = pix / WL, x = pix % WL;
  float acc[8];
#pragma unroll
  for (int o=0;o<8;o++) acc[o] = bias[chunk*8+o];
  for (int ic=0; ic<IC; ic++) {
    const float* ip = in + ic*LRPIX;
    const float* wp = w + (chunk*8*IC + ic)*9;
#pragma unroll
    for (int ky=0; ky<3; ky++) {
      int yy = y+ky-1;
      if (yy < 0 || yy >= HL) continue;
#pragma unroll
      for (int kx=0; kx<3; kx++) {
        int xx = x+kx-1;
        if (xx < 0 || xx >= WL) continue;
        float v = ip[yy*WL+xx];
#pragma unroll
        for (int o=0;o<8;o++)
          acc[o] += v * wp[o*IC*9 + ky*3+kx];
      }
    }
  }
#pragma unroll
  for (int o=0;o<8;o++)
    out[(chunk*8+o)*LRPIX + pix] = gelu_f(acc[o]);
}

// ---------------- bicubic upsample (matches jax.image.resize 'cubic') ------
__global__ void bicubic_up(const float* __restrict__ lr, float* __restrict__ up) {
  int id = blockIdx.x*blockDim.x + threadIdx.x;
  if (id >= 3*NPIX) return;
  int c = id / NPIX, p = id % NPIX;
  int hy = p / WH, hx = p % WH;
  float sx = (hx+0.5f)*0.25f - 0.5f;
  float sy = (hy+0.5f)*0.25f - 0.5f;
  int bx = (int)floorf(sx), by = (int)floorf(sy);
  float wx[4], wy[4];
  int ix[4], iy[4];
  float sumx = 0.f, sumy = 0.f;
#pragma unroll
  for (int i=0;i<4;i++) {
    int j = bx-1+i;
    float wv = (j>=0 && j<WL) ? keys_cubic(sx - (float)j) : 0.f;
    wx[i] = wv; ix[i] = min(max(j,0), WL-1); sumx += wv;
    j = by-1+i;
    wv = (j>=0 && j<HL) ? keys_cubic(sy - (float)j) : 0.f;
    wy[i] = wv; iy[i] = min(max(j,0), HL-1); sumy += wv;
  }
  float inx = 1.f/sumx, iny = 1.f/sumy;
  const float* src = lr + c*LRPIX;
  float acc = 0.f;
#pragma unroll
  for (int i=0;i<4;i++) {
    float rowv = 0.f;
#pragma unroll
    for (int j=0;j<4;j++) rowv += wx[j]*src[iy[i]*WL + ix[j]];
    acc += wy[i]*rowv;
  }
  up[c*NPIX + p] = acc * inx * iny;
}

// ---------------- weight prep: fp32 -> fp16, transposed to n-major ----------
// out layout: Wt0[256][128] | Wth[4][256][256] | Whd[256][256]
__global__ void prep_weights(const float* __restrict__ w0, const float* __restrict__ wh,
                             const float* __restrict__ kw, const float* __restrict__ gw,
                             _Float16* __restrict__ out) {
  int id = blockIdx.x*blockDim.x + threadIdx.x;
  if (id < 256*128) {
    int n = id >> 7, k = id & 127;
    out[id] = (_Float16)((k < 106) ? w0[k*HID + n] : 0.f);
  } else if (id < 256*128 + 4*256*256) {
    int t = id - 256*128;
    int L = t >> 16, r = t & 65535;
    int n = r >> 8, k = r & 255;
    out[id] = (_Float16)wh[(L*256 + k)*256 + n];
  } else if (id < 256*128 + 4*256*256 + 256*256) {
    int t = id - (256*128 + 4*256*256);
    int n = t >> 8, k = t & 255;
    float v = (n < 196) ? kw[k*196 + n] : ((n < 200) ? gw[k*4 + (n-196)] : 0.f);
    out[id] = (_Float16)v;
  }
}

// ---------------- fused per-pixel MLP (MFMA) + softmax + 7x7 sum ------------
// 512 threads (8 waves), 64 consecutive HR pixels (one HR row segment).
// Wave w computes all 64 rows x cols [32w, 32w+32) -> acc[4][2] fragments.
#define PMT 512
__global__ __launch_bounds__(PMT, 4)
void pixel_mlp2(const float* __restrict__ f, const float* __restrict__ lr,
                const _Float16* __restrict__ Wt0, const float* __restrict__ b0,
                const _Float16* __restrict__ Wth, const float* __restrict__ bh,
                const _Float16* __restrict__ Whd, const float* __restrict__ kb,
                const float* __restrict__ gb, float* __restrict__ res0) {
  __shared__ _Float16 x_lds[64*128];   // 16 KB, swizzled
  __shared__ _Float16 h_lds[64*256];   // 32 KB, swizzled
  __shared__ _Float16 kbuf[64*208];    // 26 KB, logits (200 used)
  const int tid = threadIdx.x;
  const int lane = tid & 63;
  const int wave = tid >> 6;
  const int n0 = blockIdx.x * 64;
  const int hy = n0 / WH;                       // block-uniform (64 | 320)
  const int hx0 = n0 % WH;
  const float ly = (hy+0.5f)*0.25f - 0.5f;
  const int byi = min(max((int)floorf(ly),0), HL-1);
  const float fy = ly - floorf(ly);

  // ---- Phase A: x = [cfeat(64) | PE(40) | fx fy | pad] as fp16, swizzled ----
#pragma unroll
  for (int i = 0; i < 16; i++) {
    int idx = tid + i*PMT;
    int k = idx >> 6, p = idx & 63;
    int hx = hx0 + p;
    float v = 0.f;
    if (k < 64) {
      float lx = (hx+0.5f)*0.25f - 0.5f;
      int bxi = min(max((int)floorf(lx),0), WL-1);
      v = f[k*LRPIX + byi*WL + bxi];
    } else if (k < 104) {
      int band = (k-64) >> 2, r = (k-64) & 3;
      float freq = (float)(1<<band) * 3.14159265358979323846f;
      float hxn = (hx+0.5f)/320.0f*2.0f - 1.0f;
      float hyn = (hy+0.5f)/320.0f*2.0f - 1.0f;
      float arg = ((r<2) ? hxn : hyn) * freq;
      v = (r&1) ? cosf(arg) : sinf(arg);
    } else if (k == 104) {
      float lx = (hx+0.5f)*0.25f - 0.5f;
      v = lx - floorf(lx);
    } else if (k == 105) {
      v = fy;
    }
    x_lds[p*128 + (k ^ ((p&7)<<3))] = (_Float16)v;
  }
  __syncthreads();

  const int col = lane & 15;
  const int koff = (lane>>4)*8;
  const int nb = wave*32;

  f32x4 acc[4][2];
  const f32x4 vzero = {0.f,0.f,0.f,0.f};

  // ---- layer 0: x[64x128] @ Wt0 -> h ----
#pragma unroll
  for (int mi=0;mi<4;mi++)
#pragma unroll
    for (int ni=0;ni<2;ni++) acc[mi][ni] = vzero;
#pragma unroll
  for (int ks=0; ks<4; ks++) {
    int k0 = ks*32 + koff;
    half8 av[4], bv[2];
#pragma unroll
    for (int mi=0;mi<4;mi++) {
      int row = mi*16 + col;
      av[mi] = *(const half8*)&x_lds[row*128 + (k0 ^ ((row&7)<<3))];
    }
#pragma unroll
    for (int ni=0;ni<2;ni++) {
      int n = nb + ni*16 + col;
      bv[ni] = *(const half8*)&Wt0[n*128 + k0];
    }
#pragma unroll
    for (int mi=0;mi<4;mi++)
#pragma unroll
      for (int ni=0;ni<2;ni++)
        acc[mi][ni] = __builtin_amdgcn_mfma_f32_16x16x32_f16(av[mi], bv[ni], acc[mi][ni], 0,0,0);
  }
  {
    float bias0 = b0[nb + col], bias1 = b0[nb + 16 + col];
#pragma unroll
    for (int mi=0;mi<4;mi++)
#pragma unroll
      for (int ni=0;ni<2;ni++) {
        float bb = ni ? bias1 : bias0;
#pragma unroll
        for (int r=0;r<4;r++) {
          int row = mi*16 + (lane>>4)*4 + r;
          int c = nb + ni*16 + col;
          h_lds[row*256 + (c ^ ((row&7)<<3))] = (_Float16)gelu_f(acc[mi][ni][r] + bb);
        }
      }
  }
  __syncthreads();

  // ---- 4 hidden layers: h[64x256] @ Wth[L], in-place LDS update ----
  for (int L=0; L<4; L++) {
    const _Float16* W = Wth + L*HID*HID;
#pragma unroll
    for (int mi=0;mi<4;mi++)
#pragma unroll
      for (int ni=0;ni<2;ni++) acc[mi][ni] = vzero;
#pragma unroll
    for (int ks=0; ks<8; ks++) {
      int k0 = ks*32 + koff;
      half8 av[4], bv[2];
#pragma unroll
      for (int mi=0;mi<4;mi++) {
        int row = mi*16 + col;
        av[mi] = *(const half8*)&h_lds[row*256 + (k0 ^ ((row&7)<<3))];
      }
#pragma unroll
      for (int ni=0;ni<2;ni++) {
        int n = nb + ni*16 + col;
        bv[ni] = *(const half8*)&W[n*256 + k0];
      }
#pragma unroll
      for (int mi=0;mi<4;mi++)
#pragma unroll
        for (int ni=0;ni<2;ni++)
          acc[mi][ni] = __builtin_amdgcn_mfma_f32_16x16x32_f16(av[mi], bv[ni], acc[mi][ni], 0,0,0);
    }
    __syncthreads();   // everyone done READING h before in-place overwrite
    {
      float bias0 = bh[L*HID + nb + col], bias1 = bh[L*HID + nb + 16 + col];
#pragma unroll
      for (int mi=0;mi<4;mi++)
#pragma unroll
        for (int ni=0;ni<2;ni++) {
          float bb = ni ? bias1 : bias0;
#pragma unroll
          for (int r=0;r<4;r++) {
            int row = mi*16 + (lane>>4)*4 + r;
            int c = nb + ni*16 + col;
            h_lds[row*256 + (c ^ ((row&7)<<3))] = (_Float16)gelu_f(acc[mi][ni][r] + bb);
          }
        }
    }
    __syncthreads();
  }

  // ---- head: h @ Whd -> 200 logits per pixel (cols >=200 are zero-weight) ----
#pragma unroll
  for (int mi=0;mi<4;mi++)
#pragma unroll
    for (int ni=0;ni<2;ni++) acc[mi][ni] = vzero;
#pragma unroll
  for (int ks=0; ks<8; ks++) {
    int k0 = ks*32 + koff;
    half8 av[4], bv[2];
#pragma unroll
    for (int mi=0;mi<4;mi++) {
      int row = mi*16 + col;
      av[mi] = *(const half8*)&h_lds[row*256 + (k0 ^ ((row&7)<<3))];
    }
#pragma unroll
    for (int ni=0;ni<2;ni++) {
      int n = nb + ni*16 + col;
      bv[ni] = *(const half8*)&Whd[n*256 + k0];
    }
#pragma unroll
    for (int mi=0;mi<4;mi++)
#pragma unroll
      for (int ni=0;ni<2;ni++)
        acc[mi][ni] = __builtin_amdgcn_mfma_f32_16x16x32_f16(av[mi], bv[ni], acc[mi][ni], 0,0,0);
  }
  {
#pragma unroll
    for (int ni=0;ni<2;ni++) {
      int j = nb + ni*16 + col;
      if (j < 200) {
        float bb = (j < 196) ? kb[j] : gb[j-196];
#pragma unroll
        for (int mi=0;mi<4;mi++)
#pragma unroll
          for (int r=0;r<4;r++) {
            int row = mi*16 + (lane>>4)*4 + r;
            kbuf[row*208 + j] = (_Float16)(acc[mi][ni][r] + bb);
          }
      }
    }
  }
  __syncthreads();

  // ---- Phase E: softmaxes + gated 7x7 weighted sum; 8 threads per pixel ----
  {
    int p = tid >> 3, q = tid & 7;
    int hx = hx0 + p;
    float lx = (hx+0.5f)*0.25f - 0.5f;
    int bxi = min(max((int)floorf(lx),0), WL-1);
    const _Float16* kp = &kbuf[p*208];
    // gate softmax (all 8 threads redundantly)
    float g0=(float)kp[196], g1=(float)kp[197], g2=(float)kp[198], g3=(float)kp[199];
    float gm = fmaxf(fmaxf(g0,g1), fmaxf(g2,g3));
    g0=__expf(g0-gm); g1=__expf(g1-gm); g2=__expf(g2-gm); g3=__expf(g3-gm);
    float gs = 1.0f/(g0+g1+g2+g3);
    float gate[4] = {g0*gs, g1*gs, g2*gs, g3*gs};
    // per-head max/sum by threads q<4
    float mh = -1e30f, sh = 0.f;
    if (q < 4) {
      for (int t=0;t<K2;t++) mh = fmaxf(mh, (float)kp[q*K2+t]);
      for (int t=0;t<K2;t++) sh += __expf((float)kp[q*K2+t]-mh);
    }
    int base = lane & ~7;
    float m[4], s[4], gos[4];
#pragma unroll
    for (int h=0; h<4; h++) {
      m[h] = __shfl(mh, base+h);
      s[h] = __shfl(sh, base+h);
    }
#pragma unroll
    for (int h=0; h<4; h++) gos[h] = gate[h]/s[h];
    float r0=0.f, r1=0.f, r2=0.f;
    if (q < 7) {
      int dy = q-3;
      int ny = min(max(byi+dy,0),HL-1);
#pragma unroll
      for (int i=0;i<7;i++) {
        int t = q*7+i;
        int nx = min(max(bxi+i-3,0),WL-1);
        float wq = gos[0]*__expf((float)kp[t]-m[0]) + gos[1]*__expf((float)kp[K2+t]-m[1])
                 + gos[2]*__expf((float)kp[2*K2+t]-m[2]) + gos[3]*__expf((float)kp[3*K2+t]-m[3]);
        int o = ny*WL + nx;
        r0 += wq*lr[o]; r1 += wq*lr[LRPIX+o]; r2 += wq*lr[2*LRPIX+o];
      }
    }
#pragma unroll
    for (int msk=1; msk<8; msk<<=1) {
      r0 += __shfl_xor(r0, msk);
      r1 += __shfl_xor(r1, msk);
      r2 += __shfl_xor(r2, msk);
    }
    if (q == 0) {
      int n = n0 + p;
      res0[n] = r0; res0[NPIX+n] = r1; res0[2*NPIX+n] = r2;
    }
  }
}

// ---------------- refiner conv0: groups=3, 2ch -> 16ch, GELU ----------------
__global__ void rconv0(const float* __restrict__ lrup, const float* __restrict__ res0,
                       const float* __restrict__ w, const float* __restrict__ bias,
                       float* __restrict__ out) {
  int id = blockIdx.x*blockDim.x + threadIdx.x;
  if (id >= 3*NPIX) return;
  int g = id / NPIX, p = id % NPIX;
  int y = p / WH, x = p % WH;
  float acc[16];
#pragma unroll
  for (int o=0;o<16;o++) acc[o] = bias[g*16+o];
#pragma unroll
  for (int ic=0; ic<2; ic++) {
    const float* src = (ic==0 ? lrup : res0) + g*NPIX;
#pragma unroll
    for (int ky=0;ky<3;ky++) {
      int yy = y+ky-1;
      if (yy<0||yy>=HH) continue;
#pragma unroll
      for (int kx=0;kx<3;kx++) {
        int xx = x+kx-1;
        if (xx<0||xx>=WH) continue;
        float v = src[yy*WH+xx];
#pragma unroll
        for (int o=0;o<16;o++)
          acc[o] += v * w[((g*16+o)*2+ic)*9 + ky*3+kx];
      }
    }
  }
#pragma unroll
  for (int o=0;o<16;o++)
    out[(g*16+o)*NPIX + p] = gelu_f(acc[o]);
}

// ---------------- refiner conv1: groups=3, 16ch -> 16ch, GELU ---------------
__global__ void rconv1(const float* __restrict__ hr0, const float* __restrict__ w,
                       const float* __restrict__ bias, float* __restrict__ out) {
  int id = blockIdx.x*blockDim.x + threadIdx.x;
  if (id >= 3*NPIX) return;
  int g = id / NPIX, p = id % NPIX;
  int y = p / WH, x = p % WH;
  float acc[16];
#pragma unroll
  for (int o=0;o<16;o++) acc[o] = bias[g*16+o];
  for (int ic=0; ic<16; ic++) {
    const float* src = hr0 + (g*16+ic)*NPIX;
#pragma unroll
    for (int ky=0;ky<3;ky++) {
      int yy = y+ky-1;
      if (yy<0||yy>=HH) continue;
#pragma unroll
      for (int kx=0;kx<3;kx++) {
        int xx = x+kx-1;
        if (xx<0||xx>=WH) continue;
        float v = src[yy*WH+xx];
#pragma unroll
        for (int o=0;o<16;o++)
          acc[o] += v * w[((g*16+o)*16+ic)*9 + ky*3+kx];
      }
    }
  }
#pragma unroll
  for (int o=0;o<16;o++)
    out[(g*16+o)*NPIX + p] = gelu_f(acc[o]);
}

// --------- refiner conv2 (16->1 per group) + sr + gray fusion + clip --------
__global__ void rconv2_fuse(const float* __restrict__ hr1, const float* __restrict__ lrup,
                            const float* __restrict__ res0, const float* __restrict__ w,
                            const float* __restrict__ bias, float* __restrict__ out) {
  int p = blockIdx.x*blockDim.x + threadIdx.x;
  if (p >= NPIX) return;
  int y = p / WH, x = p % WH;
  float sr[3], lu[3];
#pragma unroll
  for (int c=0;c<3;c++) {
    float acc = bias[c];
    for (int ic=0; ic<16; ic++) {
      const float* src = hr1 + (c*16+ic)*NPIX;
#pragma unroll
      for (int ky=0;ky<3;ky++) {
        int yy=y+ky-1; if (yy<0||yy>=HH) continue;
#pragma unroll
        for (int kx=0;kx<3;kx++) {
          int xx=x+kx-1; if (xx<0||xx>=WH) continue;
          acc += src[yy*WH+xx] * w[(c*16+ic)*9 + ky*3+kx];
        }
      }
    }
    float l = lrup[c*NPIX+p];
    lu[c]=l;
    float srv = l + res0[c*NPIX+p] + acc;
    sr[c] = fminf(fmaxf(srv,0.f),1.f);
  }
  float delta = 0.2989f*(sr[0]-lu[0]) + 0.587f*(sr[1]-lu[1]) + 0.114f*(sr[2]-lu[2]);
#pragma unroll
  for (int c=0;c<3;c++)
    out[c*NPIX+p] = fminf(fmaxf(lu[c]+delta,0.f),1.f);
}

// ---------------------------------------------------------------------------
extern "C" void kernel_launch(void* const* d_in, const int* in_sizes, int n_in,
                              void* d_out, int out_size, void* d_ws, size_t ws_size,
                              hipStream_t stream) {
  const float* lr     = (const float*)d_in[0];
  const float* enc_w0 = (const float*)d_in[1];
  const float* enc_b0 = (const float*)d_in[2];
  const float* enc_wh = (const float*)d_in[3];
  const float* enc_bh = (const float*)d_in[4];
  const float* mlp_w0 = (const float*)d_in[5];
  const float* mlp_b0 = (const float*)d_in[6];
  const float* mlp_wh = (const float*)d_in[7];
  const float* mlp_bh = (const float*)d_in[8];
  const float* kern_w = (const float*)d_in[9];
  const float* kern_b = (const float*)d_in[10];
  const float* gate_w = (const float*)d_in[11];
  const float* gate_b = (const float*)d_in[12];
  const float* ref_w0 = (const float*)d_in[13];
  const float* ref_b0 = (const float*)d_in[14];
  const float* ref_w1 = (const float*)d_in[15];
  const float* ref_b1 = (const float*)d_in[16];
  const float* ref_w2 = (const float*)d_in[17];
  const float* ref_b2 = (const float*)d_in[18];
  float* out = (float*)d_out;
  float* ws = (float*)d_ws;

  float* f_a  = ws;                 // 409600 floats (reused for fp16 weights)
  float* f_b  = ws + 409600;        // 409600
  float* lrup = ws + 819200;        // 307200
  float* res0 = ws + 1126400;       // 307200
  float* hr0  = ws + 1433600;       // 4915200
  float* hr1  = ws + 6348800;       // 4915200

  // fp16 transposed weights live in f_a's region (dead after enc chain):
  // 360448 halfs = 720896 B <= 1.6 MB.
  _Float16* Wt0 = (_Float16*)f_a;
  _Float16* Wth = Wt0 + 256*128;
  _Float16* Whd = Wth + 4*256*256;

  // encoder: 3->64 then 3x (64->64), ping-pong f_a/f_b (ends in f_b)
  enc_conv<<<200, 256, 0, stream>>>(lr, enc_w0, enc_b0, f_a, 3);
  enc_conv<<<200, 256, 0, stream>>>(f_a, enc_wh + 0*36864, enc_bh + 0,   f_b, 64);
  enc_conv<<<200, 256, 0, stream>>>(f_b, enc_wh + 1*36864, enc_bh + 64,  f_a, 64);
  enc_conv<<<200, 256, 0, stream>>>(f_a, enc_wh + 2*36864, enc_bh + 128, f_b, 64);

  bicubic_up<<<1200, 256, 0, stream>>>(lr, lrup);

  // f_a now dead -> build fp16 weights there
  prep_weights<<<1408, 256, 0, stream>>>(mlp_w0, mlp_wh, kern_w, gate_w, Wt0);

  pixel_mlp2<<<1600, PMT, 0, stream>>>(f_b, lr, Wt0, mlp_b0, Wth, mlp_bh,
                                       Whd, kern_b, gate_b, res0);

  rconv0<<<1200, 256, 0, stream>>>(lrup, res0, ref_w0, ref_b0, hr0);
  rconv1<<<1200, 256, 0, stream>>>(hr0, ref_w1, ref_b1, hr1);
  rconv2_fuse<<<400, 256, 0, stream>>>(hr1, lrup, res0, ref_w2, ref_b2, out);
}

// Round 4
// 685.597 us; speedup vs baseline: 2.5834x; 1.1162x over previous
//
#include <hip/hip_runtime.h>
#include <math.h>

// ---------------------------------------------------------------------------
// SRModel. Round 4: pixel MLP hidden layers ping-pong between two LDS buffers
// (no in-place update -> no read/write hazard class); kbuf aliases hB.
// Keeps round-3 wins: fast sigmoid GELU, scalarized conv weights (blockIdx.y),
// MFMA-fragment-packed weights, stride-210 kbuf.
// ---------------------------------------------------------------------------

#define HL 80
#define WL 80
#define HH 320
#define WH 320
#define NPIX (HH*WH)      // 102400
#define LRPIX (HL*WL)     // 6400
#define HID 256
#define K2 49

typedef _Float16 half8 __attribute__((ext_vector_type(8)));
typedef float f32x4 __attribute__((ext_vector_type(4)));

// gelu(x) = 0.5x(1+tanh(c*(x+0.044715x^3))) == x * sigmoid(2c*(x+0.044715x^3))
__device__ __forceinline__ float gelu_f(float x) {
  float z = 1.5957691216057308f * (x + 0.044715f*x*x*x);
  return x / (1.0f + __expf(-z));
}

__device__ __forceinline__ float keys_cubic(float x) {
  x = fabsf(x);
  if (x >= 2.0f) return 0.0f;
  if (x >= 1.0f) return ((-0.5f*x + 2.5f)*x - 4.0f)*x + 2.0f;
  return ((1.5f*x - 2.5f)*x)*x + 1.0f;
}

// ---------------- encoder conv3x3 + GELU (SAME, zero pad) -------------------
// grid (25, 8): blockIdx.y = chunk of 8 output channels (scalar weights).
__global__ void enc_conv(const float* __restrict__ in, const float* __restrict__ w,
                         const float* __restrict__ bias, float* __restrict__ out,
                         int IC) {
  int pix = blockIdx.x*blockDim.x + threadIdx.x;
  int chunk = blockIdx.y;
  int y = pix / WL, x = pix % WL;
  float acc[8];
#pragma unroll
  for (int o=0;o<8;o++) acc[o] = bias[chunk*8+o];
  for (int ic=0; ic<IC; ic++) {
    const float* ip = in + ic*LRPIX;
    const float* wp = w + (chunk*8*IC + ic)*9;
#pragma unroll
    for (int ky=0; ky<3; ky++) {
      int yy = y+ky-1;
      if (yy < 0 || yy >= HL) continue;
#pragma unroll
      for (int kx=0; kx<3; kx++) {
        int xx = x+kx-1;
        if (xx < 0 || xx >= WL) continue;
        float v = ip[yy*WL+xx];
#pragma unroll
        for (int o=0;o<8;o++)
          acc[o] += v * wp[o*IC*9 + ky*3+kx];
      }
    }
  }
#pragma unroll
  for (int o=0;o<8;o++)
    out[(chunk*8+o)*LRPIX + pix] = gelu_f(acc[o]);
}

// ---------------- bicubic upsample (matches jax.image.resize 'cubic') ------
__global__ void bicubic_up(const float* __restrict__ lr, float* __restrict__ up) {
  int id = blockIdx.x*blockDim.x + threadIdx.x;
  if (id >= 3*NPIX) return;
  int c = id / NPIX, p = id % NPIX;
  int hy = p / WH, hx = p % WH;
  float sx = (hx+0.5f)*0.25f - 0.5f;
  float sy = (hy+0.5f)*0.25f - 0.5f;
  int bx = (int)floorf(sx), by = (int)floorf(sy);
  float wx[4], wy[4];
  int ix[4], iy[4];
  float sumx = 0.f, sumy = 0.f;
#pragma unroll
  for (int i=0;i<4;i++) {
    int j = bx-1+i;
    float wv = (j>=0 && j<WL) ? keys_cubic(sx - (float)j) : 0.f;
    wx[i] = wv; ix[i] = min(max(j,0), WL-1); sumx += wv;
    j = by-1+i;
    wv = (j>=0 && j<HL) ? keys_cubic(sy - (float)j) : 0.f;
    wy[i] = wv; iy[i] = min(max(j,0), HL-1); sumy += wv;
  }
  float inx = 1.f/sumx, iny = 1.f/sumy;
  const float* src = lr + c*LRPIX;
  float acc = 0.f;
#pragma unroll
  for (int i=0;i<4;i++) {
    float rowv = 0.f;
#pragma unroll
    for (int j=0;j<4;j++) rowv += wx[j]*src[iy[i]*WL + ix[j]];
    acc += wy[i]*rowv;
  }
  up[c*NPIX + p] = acc * inx * iny;
}

// ------- weight prep: fp32 -> fp16, packed in MFMA B-fragment order --------
// Fragment (16x16x32 f16 B): lane l: col = l&15, k = kt*32 + (l>>4)*8 + e.
// Linear: (((ntile*KT + ktile)*64 + lane)*8 + e).
__global__ void prep_weights(const float* __restrict__ w0, const float* __restrict__ wh,
                             const float* __restrict__ kw, const float* __restrict__ gw,
                             _Float16* __restrict__ out) {
  int idx = blockIdx.x*blockDim.x + threadIdx.x;
  int e = idx & 7, lane = (idx>>3)&63;
  int kf = (lane>>4)*8 + e;     // k within 32-tile
  int nf = lane & 15;           // n within 16-tile
  if (idx < 32768) {
    int t = idx >> 9;           // 0..63
    int kt = t & 3, nt = t >> 2;
    int k = kt*32 + kf, n = nt*16 + nf;
    out[idx] = (_Float16)((k < 106) ? w0[k*HID + n] : 0.f);
  } else if (idx < 32768 + 4*65536) {
    int r = idx - 32768;
    int L = r >> 16; r &= 65535;
    int t = r >> 9;             // 0..127
    int kt = t & 7, nt = t >> 3;
    int k = kt*32 + kf, n = nt*16 + nf;
    out[idx] = (_Float16)wh[(L*HID + k)*HID + n];
  } else if (idx < 32768 + 5*65536) {
    int r = idx - (32768 + 4*65536);
    int t = r >> 9;
    int kt = t & 7, nt = t >> 3;
    int k = kt*32 + kf, n = nt*16 + nf;
    float v = (n < 196) ? kw[k*196 + n] : ((n < 200) ? gw[k*4 + (n-196)] : 0.f);
    out[idx] = (_Float16)v;
  }
}

// ---------------- fused per-pixel MLP (MFMA) + softmax + 7x7 sum ------------
// 512 threads (8 waves), 64 consecutive HR pixels. Hidden state ping-pongs
// hA <-> hB (reads and writes always disjoint buffers; 1 barrier/layer).
#define PMT 512
__global__ __launch_bounds__(PMT, 4)
void pixel_mlp2(const float* __restrict__ f, const float* __restrict__ lr,
                const _Float16* __restrict__ Wt0, const float* __restrict__ b0,
                const _Float16* __restrict__ Wth, const float* __restrict__ bh,
                const _Float16* __restrict__ Whd, const float* __restrict__ kb,
                const float* __restrict__ gb, float* __restrict__ res0) {
  // layout: x[8192] | hA[16384] | hB[16384]  (halfs) = 80 KB total
  __shared__ _Float16 smem[8192 + 16384 + 16384];
  _Float16* x_lds = smem;
  _Float16* hA    = smem + 8192;
  _Float16* hB    = smem + 8192 + 16384;
  _Float16* kbuf  = hB;              // alias: hB dead when kbuf is written

  const int tid = threadIdx.x;
  const int lane = tid & 63;
  const int wave = tid >> 6;
  const int n0 = blockIdx.x * 64;
  const int hy = n0 / WH;                       // block-uniform (64 | 320)
  const int hx0 = n0 % WH;
  const float ly = (hy+0.5f)*0.25f - 0.5f;
  const int byi = min(max((int)floorf(ly),0), HL-1);
  const float fy = ly - floorf(ly);

  // ---- Phase A: x = [cfeat(64) | PE(40) | fx fy | pad] fp16, swizzled ----
#pragma unroll
  for (int i = 0; i < 16; i++) {
    int idx = tid + i*PMT;
    int k = idx >> 6, p = idx & 63;
    int hx = hx0 + p;
    float v = 0.f;
    if (k < 64) {
      float lx = (hx+0.5f)*0.25f - 0.5f;
      int bxi = min(max((int)floorf(lx),0), WL-1);
      v = f[k*LRPIX + byi*WL + bxi];
    } else if (k < 104) {
      int band = (k-64) >> 2, r = (k-64) & 3;
      float freq = (float)(1<<band) * 3.14159265358979323846f;
      float hxn = (hx+0.5f)/320.0f*2.0f - 1.0f;
      float hyn = (hy+0.5f)/320.0f*2.0f - 1.0f;
      float arg = ((r<2) ? hxn : hyn) * freq;
      v = (r&1) ? cosf(arg) : sinf(arg);
    } else if (k == 104) {
      float lx = (hx+0.5f)*0.25f - 0.5f;
      v = lx - floorf(lx);
    } else if (k == 105) {
      v = fy;
    }
    x_lds[p*128 + (k ^ ((p&7)<<3))] = (_Float16)v;
  }
  __syncthreads();

  const int col = lane & 15;
  const int koff = (lane>>4)*8;

  f32x4 acc[4][2];
  const f32x4 vzero = {0.f,0.f,0.f,0.f};
  const half8* B0 = (const half8*)Wt0;
  const half8* BH = (const half8*)Whd;

  // ---- layer 0: x[64x128] @ W0 -> hA ----
#pragma unroll
  for (int mi=0;mi<4;mi++)
#pragma unroll
    for (int ni=0;ni<2;ni++) acc[mi][ni] = vzero;
#pragma unroll
  for (int ks=0; ks<4; ks++) {
    int k0 = ks*32 + koff;
    half8 av[4], bv[2];
#pragma unroll
    for (int mi=0;mi<4;mi++) {
      int row = mi*16 + col;
      av[mi] = *(const half8*)&x_lds[row*128 + (k0 ^ ((row&7)<<3))];
    }
#pragma unroll
    for (int ni=0;ni<2;ni++)
      bv[ni] = B0[((wave*2+ni)*4 + ks)*64 + lane];   // coalesced 1KB/wave
#pragma unroll
    for (int mi=0;mi<4;mi++)
#pragma unroll
      for (int ni=0;ni<2;ni++)
        acc[mi][ni] = __builtin_amdgcn_mfma_f32_16x16x32_f16(av[mi], bv[ni], acc[mi][ni], 0,0,0);
  }
  {
    int nb = wave*32;
    float bias0 = b0[nb + col], bias1 = b0[nb + 16 + col];
#pragma unroll
    for (int mi=0;mi<4;mi++)
#pragma unroll
      for (int ni=0;ni<2;ni++) {
        float bb = ni ? bias1 : bias0;
#pragma unroll
        for (int r=0;r<4;r++) {
          int row = mi*16 + (lane>>4)*4 + r;
          int c = nb + ni*16 + col;
          hA[row*256 + (c ^ ((row&7)<<3))] = (_Float16)gelu_f(acc[mi][ni][r] + bb);
        }
      }
  }
  __syncthreads();

  // ---- 4 hidden layers: ping-pong hA <-> hB (L even: hA->hB, odd: hB->hA) --
  for (int L=0; L<4; L++) {
    const _Float16* hs = (L & 1) ? hB : hA;
    _Float16*       hd = (L & 1) ? hA : hB;
    const half8* BL = (const half8*)(Wth + L*65536);
#pragma unroll
    for (int mi=0;mi<4;mi++)
#pragma unroll
      for (int ni=0;ni<2;ni++) acc[mi][ni] = vzero;
#pragma unroll
    for (int ks=0; ks<8; ks++) {
      int k0 = ks*32 + koff;
      half8 av[4], bv[2];
#pragma unroll
      for (int mi=0;mi<4;mi++) {
        int row = mi*16 + col;
        av[mi] = *(const half8*)&hs[row*256 + (k0 ^ ((row&7)<<3))];
      }
#pragma unroll
      for (int ni=0;ni<2;ni++)
        bv[ni] = BL[((wave*2+ni)*8 + ks)*64 + lane];
#pragma unroll
      for (int mi=0;mi<4;mi++)
#pragma unroll
        for (int ni=0;ni<2;ni++)
          acc[mi][ni] = __builtin_amdgcn_mfma_f32_16x16x32_f16(av[mi], bv[ni], acc[mi][ni], 0,0,0);
    }
    {
      int nb = wave*32;
      float bias0 = bh[L*HID + nb + col], bias1 = bh[L*HID + nb + 16 + col];
#pragma unroll
      for (int mi=0;mi<4;mi++)
#pragma unroll
        for (int ni=0;ni<2;ni++) {
          float bb = ni ? bias1 : bias0;
#pragma unroll
          for (int r=0;r<4;r++) {
            int row = mi*16 + (lane>>4)*4 + r;
            int c = nb + ni*16 + col;
            hd[row*256 + (c ^ ((row&7)<<3))] = (_Float16)gelu_f(acc[mi][ni][r] + bb);
          }
        }
    }
    __syncthreads();   // hd complete before next layer reads it
  }

  // ---- head: hA (L3 output) @ Whd -> 200 logits; kbuf aliases hB ----
#pragma unroll
  for (int mi=0;mi<4;mi++)
#pragma unroll
    for (int ni=0;ni<2;ni++) acc[mi][ni] = vzero;
#pragma unroll
  for (int ks=0; ks<8; ks++) {
    int k0 = ks*32 + koff;
    half8 av[4], bv[2];
#pragma unroll
    for (int mi=0;mi<4;mi++) {
      int row = mi*16 + col;
      av[mi] = *(const half8*)&hA[row*256 + (k0 ^ ((row&7)<<3))];
    }
#pragma unroll
    for (int ni=0;ni<2;ni++)
      bv[ni] = BH[((wave*2+ni)*8 + ks)*64 + lane];
#pragma unroll
    for (int mi=0;mi<4;mi++)
#pragma unroll
      for (int ni=0;ni<2;ni++)
        acc[mi][ni] = __builtin_amdgcn_mfma_f32_16x16x32_f16(av[mi], bv[ni], acc[mi][ni], 0,0,0);
  }
  {
    int nb = wave*32;
#pragma unroll
    for (int ni=0;ni<2;ni++) {
      int j = nb + ni*16 + col;
      if (j < 200) {
        float bb = (j < 196) ? kb[j] : gb[j-196];
#pragma unroll
        for (int mi=0;mi<4;mi++)
#pragma unroll
          for (int r=0;r<4;r++) {
            int row = mi*16 + (lane>>4)*4 + r;
            kbuf[row*210 + j] = (_Float16)(acc[mi][ni][r] + bb);
          }
      }
    }
  }
  __syncthreads();

  // ---- Phase E: softmaxes + gated 7x7 weighted sum; 8 threads per pixel ----
  {
    int p = tid >> 3, q = tid & 7;
    int hx = hx0 + p;
    float lx = (hx+0.5f)*0.25f - 0.5f;
    int bxi = min(max((int)floorf(lx),0), WL-1);
    const _Float16* kp = &kbuf[p*210];
    float g0=(float)kp[196], g1=(float)kp[197], g2=(float)kp[198], g3=(float)kp[199];
    float gm = fmaxf(fmaxf(g0,g1), fmaxf(g2,g3));
    g0=__expf(g0-gm); g1=__expf(g1-gm); g2=__expf(g2-gm); g3=__expf(g3-gm);
    float gs = 1.0f/(g0+g1+g2+g3);
    float gate[4] = {g0*gs, g1*gs, g2*gs, g3*gs};
    float mh = -1e30f, sh = 0.f;
    if (q < 4) {
      for (int t=0;t<K2;t++) mh = fmaxf(mh, (float)kp[q*K2+t]);
      for (int t=0;t<K2;t++) sh += __expf((float)kp[q*K2+t]-mh);
    }
    int base = lane & ~7;
    float m[4], s[4], gos[4];
#pragma unroll
    for (int h=0; h<4; h++) {
      m[h] = __shfl(mh, base+h);
      s[h] = __shfl(sh, base+h);
    }
#pragma unroll
    for (int h=0; h<4; h++) gos[h] = gate[h]/s[h];
    float r0=0.f, r1=0.f, r2=0.f;
    if (q < 7) {
      int dy = q-3;
      int ny = min(max(byi+dy,0),HL-1);
#pragma unroll
      for (int i=0;i<7;i++) {
        int t = q*7+i;
        int nx = min(max(bxi+i-3,0),WL-1);
        float wq = gos[0]*__expf((float)kp[t]-m[0]) + gos[1]*__expf((float)kp[K2+t]-m[1])
                 + gos[2]*__expf((float)kp[2*K2+t]-m[2]) + gos[3]*__expf((float)kp[3*K2+t]-m[3]);
        int o = ny*WL + nx;
        r0 += wq*lr[o]; r1 += wq*lr[LRPIX+o]; r2 += wq*lr[2*LRPIX+o];
      }
    }
#pragma unroll
    for (int msk=1; msk<8; msk<<=1) {
      r0 += __shfl_xor(r0, msk);
      r1 += __shfl_xor(r1, msk);
      r2 += __shfl_xor(r2, msk);
    }
    if (q == 0) {
      int n = n0 + p;
      res0[n] = r0; res0[NPIX+n] = r1; res0[2*NPIX+n] = r2;
    }
  }
}

// ---------------- refiner conv0: groups=3, 2ch -> 16ch, GELU ----------------
__global__ void rconv0(const float* __restrict__ lrup, const float* __restrict__ res0,
                       const float* __restrict__ w, const float* __restrict__ bias,
                       float* __restrict__ out) {
  int p = blockIdx.x*blockDim.x + threadIdx.x;
  int g = blockIdx.y;
  int y = p / WH, x = p % WH;
  float acc[16];
#pragma unroll
  for (int o=0;o<16;o++) acc[o] = bias[g*16+o];
#pragma unroll
  for (int ic=0; ic<2; ic++) {
    const float* src = (ic==0 ? lrup : res0) + g*NPIX;
#pragma unroll
    for (int ky=0;ky<3;ky++) {
      int yy = y+ky-1;
      if (yy<0||yy>=HH) continue;
#pragma unroll
      for (int kx=0;kx<3;kx++) {
        int xx = x+kx-1;
        if (xx<0||xx>=WH) continue;
        float v = src[yy*WH+xx];
#pragma unroll
        for (int o=0;o<16;o++)
          acc[o] += v * w[((g*16+o)*2+ic)*9 + ky*3+kx];
      }
    }
  }
#pragma unroll
  for (int o=0;o<16;o++)
    out[(g*16+o)*NPIX + p] = gelu_f(acc[o]);
}

// ---------------- refiner conv1: groups=3, 16ch -> 16ch, GELU ---------------
__global__ void rconv1(const float* __restrict__ hr0, const float* __restrict__ w,
                       const float* __restrict__ bias, float* __restrict__ out) {
  int p = blockIdx.x*blockDim.x + threadIdx.x;
  int g = blockIdx.y;
  int y = p / WH, x = p % WH;
  float acc[16];
#pragma unroll
  for (int o=0;o<16;o++) acc[o] = bias[g*16+o];
  for (int ic=0; ic<16; ic++) {
    const float* src = hr0 + (g*16+ic)*NPIX;
#pragma unroll
    for (int ky=0;ky<3;ky++) {
      int yy = y+ky-1;
      if (yy<0||yy>=HH) continue;
#pragma unroll
      for (int kx=0;kx<3;kx++) {
        int xx = x+kx-1;
        if (xx<0||xx>=WH) continue;
        float v = src[yy*WH+xx];
#pragma unroll
        for (int o=0;o<16;o++)
          acc[o] += v * w[((g*16+o)*16+ic)*9 + ky*3+kx];
      }
    }
  }
#pragma unroll
  for (int o=0;o<16;o++)
    out[(g*16+o)*NPIX + p] = gelu_f(acc[o]);
}

// --------- refiner conv2 (16->1 per group) + sr + gray fusion + clip --------
__global__ void rconv2_fuse(const float* __restrict__ hr1, const float* __restrict__ lrup,
                            const float* __restrict__ res0, const float* __restrict__ w,
                            const float* __restrict__ bias, float* __restrict__ out) {
  int p = blockIdx.x*blockDim.x + threadIdx.x;
  if (p >= NPIX) return;
  int y = p / WH, x = p % WH;
  float sr[3], lu[3];
#pragma unroll
  for (int c=0;c<3;c++) {
    float acc = bias[c];
    for (int ic=0; ic<16; ic++) {
      const float* src = hr1 + (c*16+ic)*NPIX;
#pragma unroll
      for (int ky=0;ky<3;ky++) {
        int yy=y+ky-1; if (yy<0||yy>=HH) continue;
#pragma unroll
        for (int kx=0;kx<3;kx++) {
          int xx=x+kx-1; if (xx<0||xx>=WH) continue;
          acc += src[yy*WH+xx] * w[(c*16+ic)*9 + ky*3+kx];
        }
      }
    }
    float l = lrup[c*NPIX+p];
    lu[c]=l;
    float srv = l + res0[c*NPIX+p] + acc;
    sr[c] = fminf(fmaxf(srv,0.f),1.f);
  }
  float delta = 0.2989f*(sr[0]-lu[0]) + 0.587f*(sr[1]-lu[1]) + 0.114f*(sr[2]-lu[2]);
#pragma unroll
  for (int c=0;c<3;c++)
    out[c*NPIX+p] = fminf(fmaxf(lu[c]+delta,0.f),1.f);
}

// ---------------------------------------------------------------------------
extern "C" void kernel_launch(void* const* d_in, const int* in_sizes, int n_in,
                              void* d_out, int out_size, void* d_ws, size_t ws_size,
                              hipStream_t stream) {
  const float* lr     = (const float*)d_in[0];
  const float* enc_w0 = (const float*)d_in[1];
  const float* enc_b0 = (const float*)d_in[2];
  const float* enc_wh = (const float*)d_in[3];
  const float* enc_bh = (const float*)d_in[4];
  const float* mlp_w0 = (const float*)d_in[5];
  const float* mlp_b0 = (const float*)d_in[6];
  const float* mlp_wh = (const float*)d_in[7];
  const float* mlp_bh = (const float*)d_in[8];
  const float* kern_w = (const float*)d_in[9];
  const float* kern_b = (const float*)d_in[10];
  const float* gate_w = (const float*)d_in[11];
  const float* gate_b = (const float*)d_in[12];
  const float* ref_w0 = (const float*)d_in[13];
  const float* ref_b0 = (const float*)d_in[14];
  const float* ref_w1 = (const float*)d_in[15];
  const float* ref_b1 = (const float*)d_in[16];
  const float* ref_w2 = (const float*)d_in[17];
  const float* ref_b2 = (const float*)d_in[18];
  float* out = (float*)d_out;
  float* ws = (float*)d_ws;

  float* f_a  = ws;                 // 409600 floats (reused for fp16 weights)
  float* f_b  = ws + 409600;        // 409600
  float* lrup = ws + 819200;        // 307200
  float* res0 = ws + 1126400;       // 307200
  float* hr0  = ws + 1433600;       // 4915200
  float* hr1  = ws + 6348800;       // 4915200

  _Float16* Wt0 = (_Float16*)f_a;   // 360448 halfs = 704 KB in f_a region
  _Float16* Wth = Wt0 + 32768;
  _Float16* Whd = Wth + 4*65536;

  enc_conv<<<dim3(25,8), 256, 0, stream>>>(lr, enc_w0, enc_b0, f_a, 3);
  enc_conv<<<dim3(25,8), 256, 0, stream>>>(f_a, enc_wh + 0*36864, enc_bh + 0,   f_b, 64);
  enc_conv<<<dim3(25,8), 256, 0, stream>>>(f_b, enc_wh + 1*36864, enc_bh + 64,  f_a, 64);
  enc_conv<<<dim3(25,8), 256, 0, stream>>>(f_a, enc_wh + 2*36864, enc_bh + 128, f_b, 64);

  bicubic_up<<<1200, 256, 0, stream>>>(lr, lrup);

  // f_a now dead -> build packed fp16 weights there
  prep_weights<<<1408, 256, 0, stream>>>(mlp_w0, mlp_wh, kern_w, gate_w, Wt0);

  pixel_mlp2<<<1600, PMT, 0, stream>>>(f_b, lr, Wt0, mlp_b0, Wth, mlp_bh,
                                       Whd, kern_b, gate_b, res0);

  rconv0<<<dim3(400,3), 256, 0, stream>>>(lrup, res0, ref_w0, ref_b0, hr0);
  rconv1<<<dim3(400,3), 256, 0, stream>>>(hr0, ref_w1, ref_b1, hr1);
  rconv2_fuse<<<400, 256, 0, stream>>>(hr1, lrup, res0, ref_w2, ref_b2, out);
}

// Round 6
// 484.558 us; speedup vs baseline: 3.6552x; 1.4149x over previous
//
#include <hip/hip_runtime.h>
#include <math.h>

// ---------------------------------------------------------------------------
// SRModel. Round 6 = Round 5 structure with the Fourier PE reverted to the
// reference's exact fp32 rounding path (libm sinf/cosf on radian-domain
// products). Round-5 lesson: revolution-domain HW trig diverges ~1e-4/feature
// from the np reference and the MLP amplifies it past threshold.
//  - pixel MLP: weights as MFMA A, activations as B -> C frag = 4 consecutive
//    neurons x 1 pixel -> packed half4 (b64) LDS stores.
//  - rcp GELU, NHWC encoder/refiner activations (float4 loads).
// ---------------------------------------------------------------------------

#define HL 80
#define WL 80
#define HH 320
#define WH 320
#define NPIX (HH*WH)      // 102400
#define LRPIX (HL*WL)     // 6400
#define HID 256
#define K2 49

typedef _Float16 half8 __attribute__((ext_vector_type(8)));
typedef _Float16 half4 __attribute__((ext_vector_type(4)));
typedef float f32x4 __attribute__((ext_vector_type(4)));

// gelu tanh-form == x * sigmoid(1.595769...*(x+0.044715x^3)); raw v_rcp (1ulp)
__device__ __forceinline__ float gelu_f(float x) {
  float u = __builtin_fmaf(0.044715f*x, x*x, x);
  float e = __expf(-1.5957691216057308f * u);
  return x * __builtin_amdgcn_rcpf(1.0f + e);
}

__device__ __forceinline__ float keys_cubic(float x) {
  x = fabsf(x);
  if (x >= 2.0f) return 0.0f;
  if (x >= 1.0f) return ((-0.5f*x + 2.5f)*x - 4.0f)*x + 2.0f;
  return ((1.5f*x - 2.5f)*x)*x + 1.0f;
}

// -------- encoder conv0: lr NCHW [3][LRPIX] -> NHWC out [LRPIX][64] --------
__global__ void enc_conv0(const float* __restrict__ in, const float* __restrict__ w,
                          const float* __restrict__ bias, float* __restrict__ out) {
  int pix = blockIdx.x*blockDim.x + threadIdx.x;
  int chunk = blockIdx.y;              // 8 oc per thread
  int y = pix / WL, x = pix % WL;
  float acc[8];
#pragma unroll
  for (int o=0;o<8;o++) acc[o] = bias[chunk*8+o];
#pragma unroll
  for (int ky=0; ky<3; ky++) {
    int yy = y+ky-1;
    if (yy < 0 || yy >= HL) continue;
#pragma unroll
    for (int kx=0; kx<3; kx++) {
      int xx = x+kx-1;
      if (xx < 0 || xx >= WL) continue;
      int o0 = yy*WL+xx;
#pragma unroll
      for (int ic=0; ic<3; ic++) {
        float v = in[ic*LRPIX + o0];
#pragma unroll
        for (int o=0;o<8;o++)
          acc[o] += v * w[((chunk*8+o)*3+ic)*9 + ky*3+kx];
      }
    }
  }
#pragma unroll
  for (int o=0;o<8;o++)
    out[pix*64 + chunk*8 + o] = gelu_f(acc[o]);
}

// -------- encoder hidden conv: NHWC in [LRPIX][64] -> NHWC out -------------
__global__ void enc_convh(const float* __restrict__ in, const float* __restrict__ w,
                          const float* __restrict__ bias, float* __restrict__ out) {
  int pix = blockIdx.x*blockDim.x + threadIdx.x;
  int chunk = blockIdx.y;
  int y = pix / WL, x = pix % WL;
  float acc[8];
#pragma unroll
  for (int o=0;o<8;o++) acc[o] = bias[chunk*8+o];
#pragma unroll
  for (int ky=0; ky<3; ky++) {
    int yy = y+ky-1;
    if (yy < 0 || yy >= HL) continue;
#pragma unroll
    for (int kx=0; kx<3; kx++) {
      int xx = x+kx-1;
      if (xx < 0 || xx >= WL) continue;
      const f32x4* src = (const f32x4*)&in[(yy*WL+xx)*64];
      int tap = ky*3+kx;
#pragma unroll
      for (int icv=0; icv<16; icv++) {
        f32x4 v = src[icv];
#pragma unroll
        for (int o=0;o<8;o++) {
          const float* wp = &w[((chunk*8+o)*64 + icv*4)*9 + tap];
          acc[o] += v[0]*wp[0] + v[1]*wp[9] + v[2]*wp[18] + v[3]*wp[27];
        }
      }
    }
  }
#pragma unroll
  for (int o=0;o<8;o++)
    out[pix*64 + chunk*8 + o] = gelu_f(acc[o]);
}

// ---------------- bicubic upsample (matches jax.image.resize 'cubic') ------
__global__ void bicubic_up(const float* __restrict__ lr, float* __restrict__ up) {
  int id = blockIdx.x*blockDim.x + threadIdx.x;
  if (id >= 3*NPIX) return;
  int c = id / NPIX, p = id % NPIX;
  int hy = p / WH, hx = p % WH;
  float sx = (hx+0.5f)*0.25f - 0.5f;
  float sy = (hy+0.5f)*0.25f - 0.5f;
  int bx = (int)floorf(sx), by = (int)floorf(sy);
  float wx[4], wy[4];
  int ix[4], iy[4];
  float sumx = 0.f, sumy = 0.f;
#pragma unroll
  for (int i=0;i<4;i++) {
    int j = bx-1+i;
    float wv = (j>=0 && j<WL) ? keys_cubic(sx - (float)j) : 0.f;
    wx[i] = wv; ix[i] = min(max(j,0), WL-1); sumx += wv;
    j = by-1+i;
    wv = (j>=0 && j<HL) ? keys_cubic(sy - (float)j) : 0.f;
    wy[i] = wv; iy[i] = min(max(j,0), HL-1); sumy += wv;
  }
  float inx = __builtin_amdgcn_rcpf(sumx), iny = __builtin_amdgcn_rcpf(sumy);
  const float* src = lr + c*LRPIX;
  float acc = 0.f;
#pragma unroll
  for (int i=0;i<4;i++) {
    float rowv = 0.f;
#pragma unroll
    for (int j=0;j<4;j++) rowv += wx[j]*src[iy[i]*WL + ix[j]];
    acc += wy[i]*rowv;
  }
  up[c*NPIX + p] = acc * inx * iny;
}

// ------- weight prep: fp32 -> fp16, packed in MFMA fragment order ----------
// lane l holds (idx0 = l&15, k = kt*32 + (l>>4)*8 + e). Used as A fragments
// (idx0 = output-neuron row). Linear: (((tile*KT + kt)*64 + lane)*8 + e).
__global__ void prep_weights(const float* __restrict__ w0, const float* __restrict__ wh,
                             const float* __restrict__ kw, const float* __restrict__ gw,
                             _Float16* __restrict__ out) {
  int idx = blockIdx.x*blockDim.x + threadIdx.x;
  int e = idx & 7, lane = (idx>>3)&63;
  int kf = (lane>>4)*8 + e;
  int nf = lane & 15;
  if (idx < 32768) {
    int t = idx >> 9;           // 0..63
    int kt = t & 3, nt = t >> 2;
    int k = kt*32 + kf, n = nt*16 + nf;
    out[idx] = (_Float16)((k < 106) ? w0[k*HID + n] : 0.f);
  } else if (idx < 32768 + 4*65536) {
    int r = idx - 32768;
    int L = r >> 16; r &= 65535;
    int t = r >> 9;             // 0..127
    int kt = t & 7, nt = t >> 3;
    int k = kt*32 + kf, n = nt*16 + nf;
    out[idx] = (_Float16)wh[(L*HID + k)*HID + n];
  } else if (idx < 32768 + 5*65536) {
    int r = idx - (32768 + 4*65536);
    int t = r >> 9;
    int kt = t & 7, nt = t >> 3;
    int k = kt*32 + kf, n = nt*16 + nf;
    float v = (n < 196) ? kw[k*196 + n] : ((n < 200) ? gw[k*4 + (n-196)] : 0.f);
    out[idx] = (_Float16)v;
  }
}

// ---------------- fused per-pixel MLP (MFMA) + softmax + 7x7 sum ------------
// 512 threads (8 waves), 64 consecutive HR pixels. Wave w owns neurons
// [32w,32w+32) (A rows, 2 tiles) x all 64 pixels (B cols, 4 tiles).
// C frag: pixel = pt*16 + (lane&15), neurons = 4 consecutive -> half4 stores.
#define PMT 512
__global__ __launch_bounds__(PMT, 4)
void pixel_mlp2(const float* __restrict__ f, const float* __restrict__ lr,
                const _Float16* __restrict__ Wt0, const float* __restrict__ b0,
                const _Float16* __restrict__ Wth, const float* __restrict__ bh,
                const _Float16* __restrict__ Whd, const float* __restrict__ kb,
                const float* __restrict__ gb, float* __restrict__ res0) {
  __shared__ _Float16 smem[8192 + 16384 + 16384];   // x | hA | hB  = 80 KB
  _Float16* x_lds = smem;
  _Float16* hA    = smem + 8192;
  _Float16* hB    = smem + 8192 + 16384;
  _Float16* kbuf  = hB;              // alias: hB dead when kbuf written

  const int tid = threadIdx.x;
  const int lane = tid & 63;
  const int wave = tid >> 6;
  const int n0 = blockIdx.x * 64;
  const int hy = n0 / WH;                       // block-uniform (64 | 320)
  const int hx0 = n0 % WH;
  const float ly = (hy+0.5f)*0.25f - 0.5f;
  const int byi = min(max((int)floorf(ly),0), HL-1);
  const float fy = ly - floorf(ly);
  const float hyn = (hy+0.5f)/320.0f*2.0f - 1.0f;   // reference rounding path

  // ---- Phase A, part 1: cfeat (k<64) from NHWC f: fully coalesced ----
#pragma unroll
  for (int i = 0; i < 8; i++) {
    int p = (tid>>6) + i*8;            // wave-uniform pixel
    int k = lane;
    int hx = hx0 + p;
    float lx = (hx+0.5f)*0.25f - 0.5f;
    int bxi = min(max((int)floorf(lx),0), WL-1);
    float v = f[(byi*WL + bxi)*64 + k];
    x_lds[p*128 + (k ^ ((p&7)<<3))] = (_Float16)v;
  }
  // ---- Phase A, part 2: k in [64,128): PE (libm trig, reference-exact
  //      fp32 rounding: freq = 2^band * pi_f32, arg = hxn*freq) ----
#pragma unroll
  for (int i = 0; i < 8; i++) {
    int p = (tid>>6) + i*8;
    int k = 64 + lane;
    int hx = hx0 + p;
    float v = 0.f;
    if (k < 104) {
      int band = (k-64) >> 2, r = (k-64) & 3;
      float freq = (float)(1<<band) * 3.14159265358979323846f;
      float hxn = (hx+0.5f)/320.0f*2.0f - 1.0f;
      float arg = ((r<2) ? hxn : hyn) * freq;
      v = (r&1) ? cosf(arg) : sinf(arg);
    } else if (k == 104) {
      float lx = (hx+0.5f)*0.25f - 0.5f;
      v = lx - floorf(lx);
    } else if (k == 105) {
      v = fy;
    }
    x_lds[p*128 + (k ^ ((p&7)<<3))] = (_Float16)v;
  }
  __syncthreads();

  const int col  = lane & 15;          // pixel-in-tile (B col / C col)
  const int koff = (lane>>4)*8;
  const int sw   = (lane&7)<<3;        // swizzle key (pixel&7 == lane&7)
  const int rbase = (lane>>4)*4;       // neuron base within 16-tile (C rows)

  f32x4 acc[2][4];
  const f32x4 vzero = {0.f,0.f,0.f,0.f};
  const half8* A0 = (const half8*)Wt0;
  const half8* AH = (const half8*)Whd;

  // ---- layer 0: W0(A) x x(B) -> hA ----
#pragma unroll
  for (int nt=0;nt<2;nt++)
#pragma unroll
    for (int pt=0;pt<4;pt++) acc[nt][pt] = vzero;
#pragma unroll
  for (int ks=0; ks<4; ks++) {
    int k0 = ks*32 + koff;
    half8 aw[2], bx[4];
#pragma unroll
    for (int nt=0;nt<2;nt++)
      aw[nt] = A0[((wave*2+nt)*4 + ks)*64 + lane];
#pragma unroll
    for (int pt=0;pt<4;pt++)
      bx[pt] = *(const half8*)&x_lds[(pt*16+col)*128 + (k0 ^ sw)];
#pragma unroll
    for (int nt=0;nt<2;nt++)
#pragma unroll
      for (int pt=0;pt<4;pt++)
        acc[nt][pt] = __builtin_amdgcn_mfma_f32_16x16x32_f16(aw[nt], bx[pt], acc[nt][pt], 0,0,0);
  }
#pragma unroll
  for (int nt=0;nt<2;nt++) {
    int nbase = wave*32 + nt*16 + rbase;
    f32x4 bb = *(const f32x4*)&b0[nbase];
#pragma unroll
    for (int pt=0;pt<4;pt++) {
      int pix = pt*16 + col;
      half4 hv;
      hv[0] = (_Float16)gelu_f(acc[nt][pt][0] + bb[0]);
      hv[1] = (_Float16)gelu_f(acc[nt][pt][1] + bb[1]);
      hv[2] = (_Float16)gelu_f(acc[nt][pt][2] + bb[2]);
      hv[3] = (_Float16)gelu_f(acc[nt][pt][3] + bb[3]);
      *(half4*)&hA[pix*256 + (nbase ^ sw)] = hv;
    }
  }
  __syncthreads();

  // ---- 4 hidden layers: ping-pong hA <-> hB ----
  for (int L=0; L<4; L++) {
    const _Float16* hs = (L & 1) ? hB : hA;
    _Float16*       hd = (L & 1) ? hA : hB;
    const half8* AL = (const half8*)(Wth + L*65536);
#pragma unroll
    for (int nt=0;nt<2;nt++)
#pragma unroll
      for (int pt=0;pt<4;pt++) acc[nt][pt] = vzero;
#pragma unroll
    for (int ks=0; ks<8; ks++) {
      int k0 = ks*32 + koff;
      half8 aw[2], bx[4];
#pragma unroll
      for (int nt=0;nt<2;nt++)
        aw[nt] = AL[((wave*2+nt)*8 + ks)*64 + lane];
#pragma unroll
      for (int pt=0;pt<4;pt++)
        bx[pt] = *(const half8*)&hs[(pt*16+col)*256 + (k0 ^ sw)];
#pragma unroll
      for (int nt=0;nt<2;nt++)
#pragma unroll
        for (int pt=0;pt<4;pt++)
          acc[nt][pt] = __builtin_amdgcn_mfma_f32_16x16x32_f16(aw[nt], bx[pt], acc[nt][pt], 0,0,0);
    }
#pragma unroll
    for (int nt=0;nt<2;nt++) {
      int nbase = wave*32 + nt*16 + rbase;
      f32x4 bb = *(const f32x4*)&bh[L*HID + nbase];
#pragma unroll
      for (int pt=0;pt<4;pt++) {
        int pix = pt*16 + col;
        half4 hv;
        hv[0] = (_Float16)gelu_f(acc[nt][pt][0] + bb[0]);
        hv[1] = (_Float16)gelu_f(acc[nt][pt][1] + bb[1]);
        hv[2] = (_Float16)gelu_f(acc[nt][pt][2] + bb[2]);
        hv[3] = (_Float16)gelu_f(acc[nt][pt][3] + bb[3]);
        *(half4*)&hd[pix*256 + (nbase ^ sw)] = hv;
      }
    }
    __syncthreads();
  }

  // ---- head: Whd(A) x hA(B) -> 200 logits/pixel into kbuf[pix][208] ----
#pragma unroll
  for (int nt=0;nt<2;nt++)
#pragma unroll
    for (int pt=0;pt<4;pt++) acc[nt][pt] = vzero;
#pragma unroll
  for (int ks=0; ks<8; ks++) {
    int k0 = ks*32 + koff;
    half8 aw[2], bx[4];
#pragma unroll
    for (int nt=0;nt<2;nt++)
      aw[nt] = AH[((wave*2+nt)*8 + ks)*64 + lane];
#pragma unroll
    for (int pt=0;pt<4;pt++)
      bx[pt] = *(const half8*)&hA[(pt*16+col)*256 + (k0 ^ sw)];
#pragma unroll
    for (int nt=0;nt<2;nt++)
#pragma unroll
      for (int pt=0;pt<4;pt++)
        acc[nt][pt] = __builtin_amdgcn_mfma_f32_16x16x32_f16(aw[nt], bx[pt], acc[nt][pt], 0,0,0);
  }
#pragma unroll
  for (int nt=0;nt<2;nt++) {
    int jb = wave*32 + nt*16 + rbase;    // multiple of 4
    if (jb < 200) {
      const float* bp = (jb < 196) ? (kb + jb) : (gb + (jb - 196));
      f32x4 bb = *(const f32x4*)bp;
#pragma unroll
      for (int pt=0;pt<4;pt++) {
        int pix = pt*16 + col;
        half4 kv;
        kv[0] = (_Float16)(acc[nt][pt][0] + bb[0]);
        kv[1] = (_Float16)(acc[nt][pt][1] + bb[1]);
        kv[2] = (_Float16)(acc[nt][pt][2] + bb[2]);
        kv[3] = (_Float16)(acc[nt][pt][3] + bb[3]);
        *(half4*)&kbuf[pix*208 + jb] = kv;
      }
    }
  }
  __syncthreads();

  // ---- Phase E: softmaxes + gated 7x7 weighted sum; 8 threads per pixel ----
  {
    int p = tid >> 3, q = tid & 7;
    int hx = hx0 + p;
    float lx = (hx+0.5f)*0.25f - 0.5f;
    int bxi = min(max((int)floorf(lx),0), WL-1);
    const _Float16* kp = &kbuf[p*208];
    float g0=(float)kp[196], g1=(float)kp[197], g2=(float)kp[198], g3=(float)kp[199];
    float gm = fmaxf(fmaxf(g0,g1), fmaxf(g2,g3));
    g0=__expf(g0-gm); g1=__expf(g1-gm); g2=__expf(g2-gm); g3=__expf(g3-gm);
    float gs = __builtin_amdgcn_rcpf(g0+g1+g2+g3);
    float gate[4] = {g0*gs, g1*gs, g2*gs, g3*gs};
    float mh = -1e30f, sh = 0.f;
    if (q < 4) {
      for (int t=0;t<K2;t++) mh = fmaxf(mh, (float)kp[q*K2+t]);
      for (int t=0;t<K2;t++) sh += __expf((float)kp[q*K2+t]-mh);
    }
    int base = lane & ~7;
    float m[4], s[4], gos[4];
#pragma unroll
    for (int h=0; h<4; h++) {
      m[h] = __shfl(mh, base+h);
      s[h] = __shfl(sh, base+h);
    }
#pragma unroll
    for (int h=0; h<4; h++) gos[h] = gate[h]*__builtin_amdgcn_rcpf(s[h]);
    float r0=0.f, r1=0.f, r2=0.f;
    if (q < 7) {
      int dy = q-3;
      int ny = min(max(byi+dy,0),HL-1);
#pragma unroll
      for (int i=0;i<7;i++) {
        int t = q*7+i;
        int nx = min(max(bxi+i-3,0),WL-1);
        float wq = gos[0]*__expf((float)kp[t]-m[0]) + gos[1]*__expf((float)kp[K2+t]-m[1])
                 + gos[2]*__expf((float)kp[2*K2+t]-m[2]) + gos[3]*__expf((float)kp[3*K2+t]-m[3]);
        int o = ny*WL + nx;
        r0 += wq*lr[o]; r1 += wq*lr[LRPIX+o]; r2 += wq*lr[2*LRPIX+o];
      }
    }
#pragma unroll
    for (int msk=1; msk<8; msk<<=1) {
      r0 += __shfl_xor(r0, msk);
      r1 += __shfl_xor(r1, msk);
      r2 += __shfl_xor(r2, msk);
    }
    if (q == 0) {
      int n = n0 + p;
      res0[n] = r0; res0[NPIX+n] = r1; res0[2*NPIX+n] = r2;
    }
  }
}

// ------ refiner conv0: groups=3, 2ch -> 16ch, GELU; out NHWC [NPIX][48] -----
__global__ void rconv0(const float* __restrict__ lrup, const float* __restrict__ res0,
                       const float* __restrict__ w, const float* __restrict__ bias,
                       float* __restrict__ out) {
  int p = blockIdx.x*blockDim.x + threadIdx.x;
  int g = blockIdx.y;
  int y = p / WH, x = p % WH;
  float acc[16];
#pragma unroll
  for (int o=0;o<16;o++) acc[o] = bias[g*16+o];
#pragma unroll
  for (int ic=0; ic<2; ic++) {
    const float* src = (ic==0 ? lrup : res0) + g*NPIX;
#pragma unroll
    for (int ky=0;ky<3;ky++) {
      int yy = y+ky-1;
      if (yy<0||yy>=HH) continue;
#pragma unroll
      for (int kx=0;kx<3;kx++) {
        int xx = x+kx-1;
        if (xx<0||xx>=WH) continue;
        float v = src[yy*WH+xx];
#pragma unroll
        for (int o=0;o<16;o++)
          acc[o] += v * w[((g*16+o)*2+ic)*9 + ky*3+kx];
      }
    }
  }
  float* dst = out + p*48 + g*16;
#pragma unroll
  for (int o=0;o<16;o++) dst[o] = gelu_f(acc[o]);
}

// ------ refiner conv1: groups=3, 16->16, GELU; NHWC in/out [NPIX][48] ------
__global__ void rconv1(const float* __restrict__ hr0, const float* __restrict__ w,
                       const float* __restrict__ bias, float* __restrict__ out) {
  int p = blockIdx.x*blockDim.x + threadIdx.x;
  int g = blockIdx.y;
  int y = p / WH, x = p % WH;
  float acc[16];
#pragma unroll
  for (int o=0;o<16;o++) acc[o] = bias[g*16+o];
#pragma unroll
  for (int ky=0;ky<3;ky++) {
    int yy = y+ky-1;
    if (yy<0||yy>=HH) continue;
#pragma unroll
    for (int kx=0;kx<3;kx++) {
      int xx = x+kx-1;
      if (xx<0||xx>=WH) continue;
      const f32x4* src = (const f32x4*)&hr0[(yy*WH+xx)*48 + g*16];
      int tap = ky*3+kx;
#pragma unroll
      for (int icv=0; icv<4; icv++) {
        f32x4 v = src[icv];
#pragma unroll
        for (int o=0;o<16;o++) {
          const float* wp = &w[((g*16+o)*16 + icv*4)*9 + tap];
          acc[o] += v[0]*wp[0] + v[1]*wp[9] + v[2]*wp[18] + v[3]*wp[27];
        }
      }
    }
  }
  float* dst = out + p*48 + g*16;
#pragma unroll
  for (int o=0;o<16;o++) dst[o] = gelu_f(acc[o]);
}

// --------- refiner conv2 (16->1 per group) + sr + gray fusion + clip --------
__global__ void rconv2_fuse(const float* __restrict__ hr1, const float* __restrict__ lrup,
                            const float* __restrict__ res0, const float* __restrict__ w,
                            const float* __restrict__ bias, float* __restrict__ out) {
  int p = blockIdx.x*blockDim.x + threadIdx.x;
  if (p >= NPIX) return;
  int y = p / WH, x = p % WH;
  float acc3[3];
#pragma unroll
  for (int c=0;c<3;c++) acc3[c] = bias[c];
#pragma unroll
  for (int ky=0;ky<3;ky++) {
    int yy=y+ky-1; if (yy<0||yy>=HH) continue;
#pragma unroll
    for (int kx=0;kx<3;kx++) {
      int xx=x+kx-1; if (xx<0||xx>=WH) continue;
      const f32x4* src = (const f32x4*)&hr1[(yy*WH+xx)*48];
      int tap = ky*3+kx;
#pragma unroll
      for (int c=0;c<3;c++) {
#pragma unroll
        for (int icv=0; icv<4; icv++) {
          f32x4 v = src[c*4 + icv];
          const float* wp = &w[(c*16 + icv*4)*9 + tap];
          acc3[c] += v[0]*wp[0] + v[1]*wp[9] + v[2]*wp[18] + v[3]*wp[27];
        }
      }
    }
  }
  float sr[3], lu[3];
#pragma unroll
  for (int c=0;c<3;c++) {
    float l = lrup[c*NPIX+p];
    lu[c]=l;
    float srv = l + res0[c*NPIX+p] + acc3[c];
    sr[c] = fminf(fmaxf(srv,0.f),1.f);
  }
  float delta = 0.2989f*(sr[0]-lu[0]) + 0.587f*(sr[1]-lu[1]) + 0.114f*(sr[2]-lu[2]);
#pragma unroll
  for (int c=0;c<3;c++)
    out[c*NPIX+p] = fminf(fmaxf(lu[c]+delta,0.f),1.f);
}

// ---------------------------------------------------------------------------
extern "C" void kernel_launch(void* const* d_in, const int* in_sizes, int n_in,
                              void* d_out, int out_size, void* d_ws, size_t ws_size,
                              hipStream_t stream) {
  const float* lr     = (const float*)d_in[0];
  const float* enc_w0 = (const float*)d_in[1];
  const float* enc_b0 = (const float*)d_in[2];
  const float* enc_wh = (const float*)d_in[3];
  const float* enc_bh = (const float*)d_in[4];
  const float* mlp_w0 = (const float*)d_in[5];
  const float* mlp_b0 = (const float*)d_in[6];
  const float* mlp_wh = (const float*)d_in[7];
  const float* mlp_bh = (const float*)d_in[8];
  const float* kern_w = (const float*)d_in[9];
  const float* kern_b = (const float*)d_in[10];
  const float* gate_w = (const float*)d_in[11];
  const float* gate_b = (const float*)d_in[12];
  const float* ref_w0 = (const float*)d_in[13];
  const float* ref_b0 = (const float*)d_in[14];
  const float* ref_w1 = (const float*)d_in[15];
  const float* ref_b1 = (const float*)d_in[16];
  const float* ref_w2 = (const float*)d_in[17];
  const float* ref_b2 = (const float*)d_in[18];
  float* out = (float*)d_out;
  float* ws = (float*)d_ws;

  float* f_a  = ws;                 // 409600 floats, NHWC [6400][64]
  float* f_b  = ws + 409600;        // 409600, NHWC
  float* lrup = ws + 819200;        // 307200, NCHW [3][NPIX]
  float* res0 = ws + 1126400;       // 307200, NCHW
  float* hr0  = ws + 1433600;       // 4915200, NHWC [NPIX][48]
  float* hr1  = ws + 6348800;       // 4915200, NHWC

  _Float16* Wt0 = (_Float16*)f_a;   // 360448 halfs = 704 KB in f_a region
  _Float16* Wth = Wt0 + 32768;
  _Float16* Whd = Wth + 4*65536;

  enc_conv0<<<dim3(25,8), 256, 0, stream>>>(lr, enc_w0, enc_b0, f_a);
  enc_convh<<<dim3(25,8), 256, 0, stream>>>(f_a, enc_wh + 0*36864, enc_bh + 0,   f_b);
  enc_convh<<<dim3(25,8), 256, 0, stream>>>(f_b, enc_wh + 1*36864, enc_bh + 64,  f_a);
  enc_convh<<<dim3(25,8), 256, 0, stream>>>(f_a, enc_wh + 2*36864, enc_bh + 128, f_b);

  bicubic_up<<<1200, 256, 0, stream>>>(lr, lrup);

  // f_a now dead -> build packed fp16 weights there
  prep_weights<<<1408, 256, 0, stream>>>(mlp_w0, mlp_wh, kern_w, gate_w, Wt0);

  pixel_mlp2<<<1600, PMT, 0, stream>>>(f_b, lr, Wt0, mlp_b0, Wth, mlp_bh,
                                       Whd, kern_b, gate_b, res0);

  rconv0<<<dim3(400,3), 256, 0, stream>>>(lrup, res0, ref_w0, ref_b0, hr0);
  rconv1<<<dim3(400,3), 256, 0, stream>>>(hr0, ref_w1, ref_b1, hr1);
  rconv2_fuse<<<400, 256, 0, stream>>>(hr1, lrup, res0, ref_w2, ref_b2, out);
}

// Round 8
// 307.377 us; speedup vs baseline: 5.7622x; 1.5764x over previous
//
#include <hip/hip_runtime.h>
#include <math.h>

// ---------------------------------------------------------------------------
// SRModel. Round 8 = Round 7 conv LDS staging (kept; reassociation-only)
// + Phase E WITHOUT exp write-back (round-7 failure: fp16-quantized softmax
// weights add ~5e-4 noise to res0, which the refiner amplifies ~10x at the
// worst pixel -> 0.0273 > 0.02). Pass 2 recomputes exp from fp16 logits,
// bit-matching the passing round-6 numerics (split max/sum reorder ~1e-7).
// ---------------------------------------------------------------------------

#define HL 80
#define WL 80
#define HH 320
#define WH 320
#define NPIX (HH*WH)      // 102400
#define LRPIX (HL*WL)     // 6400
#define HID 256
#define K2 49

typedef _Float16 half8 __attribute__((ext_vector_type(8)));
typedef _Float16 half4 __attribute__((ext_vector_type(4)));
typedef float f32x4 __attribute__((ext_vector_type(4)));

__device__ __forceinline__ float gelu_f(float x) {
  float u = __builtin_fmaf(0.044715f*x, x*x, x);
  float e = __expf(-1.5957691216057308f * u);
  return x * __builtin_amdgcn_rcpf(1.0f + e);
}

__device__ __forceinline__ float keys_cubic(float x) {
  x = fabsf(x);
  if (x >= 2.0f) return 0.0f;
  if (x >= 1.0f) return ((-0.5f*x + 2.5f)*x - 4.0f)*x + 2.0f;
  return ((1.5f*x - 2.5f)*x)*x + 1.0f;
}

// -------- encoder conv0: lr NCHW [3][LRPIX] -> NHWC out [LRPIX][64] --------
__global__ void enc_conv0(const float* __restrict__ in, const float* __restrict__ w,
                          const float* __restrict__ bias, float* __restrict__ out) {
  __shared__ float wl[216];
  int tid = threadIdx.x;
  int chunk = blockIdx.y;
  if (tid < 216) {
    int o = tid/27, r = tid - o*27, ic = r/9, tap = r - ic*9;
    wl[tap*24 + ic*8 + o] = w[((chunk*8+o)*3+ic)*9 + tap];
  }
  __syncthreads();
  int pix = blockIdx.x*blockDim.x + tid;
  int y = pix / WL, x = pix % WL;
  float acc[8];
#pragma unroll
  for (int o=0;o<8;o++) acc[o] = bias[chunk*8+o];
#pragma unroll
  for (int ky=0; ky<3; ky++) {
    int yy = y+ky-1;
    if (yy < 0 || yy >= HL) continue;
#pragma unroll
    for (int kx=0; kx<3; kx++) {
      int xx = x+kx-1;
      if (xx < 0 || xx >= WL) continue;
      int o0 = yy*WL+xx, tap = ky*3+kx;
#pragma unroll
      for (int ic=0; ic<3; ic++) {
        float v = in[ic*LRPIX + o0];
        const f32x4* wb = (const f32x4*)&wl[tap*24 + ic*8];
        f32x4 w0 = wb[0], w1 = wb[1];
#pragma unroll
        for (int o=0;o<4;o++) { acc[o] += v*w0[o]; acc[o+4] += v*w1[o]; }
      }
    }
  }
#pragma unroll
  for (int o=0;o<8;o++)
    out[pix*64 + chunk*8 + o] = gelu_f(acc[o]);
}

// -------- encoder hidden conv: NHWC in -> NHWC out; LDS weights ------------
__global__ void enc_convh(const float* __restrict__ in, const float* __restrict__ w,
                          const float* __restrict__ bias, float* __restrict__ out) {
  __shared__ float wl[4608];
  int tid = threadIdx.x;
  int chunk = blockIdx.y;
  const float* wsrc = w + chunk*8*576;     // [8 oc][64 ic][9 tap]
#pragma unroll
  for (int i=0;i<36;i++) {
    int idx = tid + i*128;
    int o = idx/576, r = idx - o*576, ic = r/9, tap = r - ic*9;
    wl[tap*512 + ic*8 + o] = wsrc[idx];
  }
  __syncthreads();
  int pix = blockIdx.x*128 + tid;
  int y = pix / WL, x = pix % WL;
  float acc[8];
#pragma unroll
  for (int o=0;o<8;o++) acc[o] = bias[chunk*8+o];
#pragma unroll
  for (int ky=0; ky<3; ky++) {
    int yy = y+ky-1;
    if (yy < 0 || yy >= HL) continue;
#pragma unroll
    for (int kx=0; kx<3; kx++) {
      int xx = x+kx-1;
      if (xx < 0 || xx >= WL) continue;
      const f32x4* src = (const f32x4*)&in[(yy*WL+xx)*64];
      const float* wt = &wl[(ky*3+kx)*512];
#pragma unroll
      for (int icv=0; icv<16; icv++) {
        f32x4 v = src[icv];
#pragma unroll
        for (int j=0;j<4;j++) {
          const f32x4* wb = (const f32x4*)&wt[(icv*4+j)*8];
          f32x4 w0 = wb[0], w1 = wb[1];
#pragma unroll
          for (int o=0;o<4;o++) { acc[o] += v[j]*w0[o]; acc[4+o] += v[j]*w1[o]; }
        }
      }
    }
  }
#pragma unroll
  for (int o=0;o<8;o++)
    out[pix*64 + chunk*8 + o] = gelu_f(acc[o]);
}

// ---------------- bicubic upsample (matches jax.image.resize 'cubic') ------
__global__ void bicubic_up(const float* __restrict__ lr, float* __restrict__ up) {
  int id = blockIdx.x*blockDim.x + threadIdx.x;
  if (id >= 3*NPIX) return;
  int c = id / NPIX, p = id % NPIX;
  int hy = p / WH, hx = p % WH;
  float sx = (hx+0.5f)*0.25f - 0.5f;
  float sy = (hy+0.5f)*0.25f - 0.5f;
  int bx = (int)floorf(sx), by = (int)floorf(sy);
  float wx[4], wy[4];
  int ix[4], iy[4];
  float sumx = 0.f, sumy = 0.f;
#pragma unroll
  for (int i=0;i<4;i++) {
    int j = bx-1+i;
    float wv = (j>=0 && j<WL) ? keys_cubic(sx - (float)j) : 0.f;
    wx[i] = wv; ix[i] = min(max(j,0), WL-1); sumx += wv;
    j = by-1+i;
    wv = (j>=0 && j<HL) ? keys_cubic(sy - (float)j) : 0.f;
    wy[i] = wv; iy[i] = min(max(j,0), HL-1); sumy += wv;
  }
  float inx = __builtin_amdgcn_rcpf(sumx), iny = __builtin_amdgcn_rcpf(sumy);
  const float* src = lr + c*LRPIX;
  float acc = 0.f;
#pragma unroll
  for (int i=0;i<4;i++) {
    float rowv = 0.f;
#pragma unroll
    for (int j=0;j<4;j++) rowv += wx[j]*src[iy[i]*WL + ix[j]];
    acc += wy[i]*rowv;
  }
  up[c*NPIX + p] = acc * inx * iny;
}

// ------- weight prep: fp32 -> fp16, packed in MFMA fragment order ----------
__global__ void prep_weights(const float* __restrict__ w0, const float* __restrict__ wh,
                             const float* __restrict__ kw, const float* __restrict__ gw,
                             _Float16* __restrict__ out) {
  int idx = blockIdx.x*blockDim.x + threadIdx.x;
  int e = idx & 7, lane = (idx>>3)&63;
  int kf = (lane>>4)*8 + e;
  int nf = lane & 15;
  if (idx < 32768) {
    int t = idx >> 9;
    int kt = t & 3, nt = t >> 2;
    int k = kt*32 + kf, n = nt*16 + nf;
    out[idx] = (_Float16)((k < 106) ? w0[k*HID + n] : 0.f);
  } else if (idx < 32768 + 4*65536) {
    int r = idx - 32768;
    int L = r >> 16; r &= 65535;
    int t = r >> 9;
    int kt = t & 7, nt = t >> 3;
    int k = kt*32 + kf, n = nt*16 + nf;
    out[idx] = (_Float16)wh[(L*HID + k)*HID + n];
  } else if (idx < 32768 + 5*65536) {
    int r = idx - (32768 + 4*65536);
    int t = r >> 9;
    int kt = t & 7, nt = t >> 3;
    int k = kt*32 + kf, n = nt*16 + nf;
    float v = (n < 196) ? kw[k*196 + n] : ((n < 200) ? gw[k*4 + (n-196)] : 0.f);
    out[idx] = (_Float16)v;
  }
}

// ---------------- fused per-pixel MLP (MFMA) + softmax + 7x7 sum ------------
#define PMT 512
__global__ __launch_bounds__(PMT, 4)
void pixel_mlp2(const float* __restrict__ f, const float* __restrict__ lr,
                const _Float16* __restrict__ Wt0, const float* __restrict__ b0,
                const _Float16* __restrict__ Wth, const float* __restrict__ bh,
                const _Float16* __restrict__ Whd, const float* __restrict__ kb,
                const float* __restrict__ gb, float* __restrict__ res0) {
  __shared__ _Float16 smem[8192 + 16384 + 16384];   // x | hA | hB  = 80 KB
  _Float16* x_lds = smem;
  _Float16* hA    = smem + 8192;
  _Float16* hB    = smem + 8192 + 16384;
  _Float16* kbuf  = hB;              // alias: hB dead when kbuf written

  const int tid = threadIdx.x;
  const int lane = tid & 63;
  const int wave = tid >> 6;
  const int n0 = blockIdx.x * 64;
  const int hy = n0 / WH;                       // block-uniform (64 | 320)
  const int hx0 = n0 % WH;
  const float ly = (hy+0.5f)*0.25f - 0.5f;
  const int byi = min(max((int)floorf(ly),0), HL-1);
  const float fy = ly - floorf(ly);
  const float hyn = (hy+0.5f)/320.0f*2.0f - 1.0f;   // reference rounding path

  // ---- Phase A, part 1: cfeat (k<64) from NHWC f ----
#pragma unroll
  for (int i = 0; i < 8; i++) {
    int p = (tid>>6) + i*8;            // wave-uniform pixel
    int k = lane;
    int hx = hx0 + p;
    float lx = (hx+0.5f)*0.25f - 0.5f;
    int bxi = min(max((int)floorf(lx),0), WL-1);
    float v = f[(byi*WL + bxi)*64 + k];
    x_lds[p*128 + (k ^ ((p&7)<<3))] = (_Float16)v;
  }
  // ---- Phase A, part 2: PE (libm trig, reference-exact fp32 rounding) ----
#pragma unroll
  for (int i = 0; i < 8; i++) {
    int p = (tid>>6) + i*8;
    int k = 64 + lane;
    int hx = hx0 + p;
    float v = 0.f;
    if (k < 104) {
      int band = (k-64) >> 2, r = (k-64) & 3;
      float freq = (float)(1<<band) * 3.14159265358979323846f;
      float hxn = (hx+0.5f)/320.0f*2.0f - 1.0f;
      float arg = ((r<2) ? hxn : hyn) * freq;
      v = (r&1) ? cosf(arg) : sinf(arg);
    } else if (k == 104) {
      float lx = (hx+0.5f)*0.25f - 0.5f;
      v = lx - floorf(lx);
    } else if (k == 105) {
      v = fy;
    }
    x_lds[p*128 + (k ^ ((p&7)<<3))] = (_Float16)v;
  }
  __syncthreads();

  const int col  = lane & 15;
  const int koff = (lane>>4)*8;
  const int sw   = (lane&7)<<3;
  const int rbase = (lane>>4)*4;

  f32x4 acc[2][4];
  const f32x4 vzero = {0.f,0.f,0.f,0.f};
  const half8* A0 = (const half8*)Wt0;
  const half8* AH = (const half8*)Whd;

  // ---- layer 0: W0(A) x x(B) -> hA ----
#pragma unroll
  for (int nt=0;nt<2;nt++)
#pragma unroll
    for (int pt=0;pt<4;pt++) acc[nt][pt] = vzero;
#pragma unroll
  for (int ks=0; ks<4; ks++) {
    int k0 = ks*32 + koff;
    half8 aw[2], bx[4];
#pragma unroll
    for (int nt=0;nt<2;nt++)
      aw[nt] = A0[((wave*2+nt)*4 + ks)*64 + lane];
#pragma unroll
    for (int pt=0;pt<4;pt++)
      bx[pt] = *(const half8*)&x_lds[(pt*16+col)*128 + (k0 ^ sw)];
#pragma unroll
    for (int nt=0;nt<2;nt++)
#pragma unroll
      for (int pt=0;pt<4;pt++)
        acc[nt][pt] = __builtin_amdgcn_mfma_f32_16x16x32_f16(aw[nt], bx[pt], acc[nt][pt], 0,0,0);
  }
#pragma unroll
  for (int nt=0;nt<2;nt++) {
    int nbase = wave*32 + nt*16 + rbase;
    f32x4 bb = *(const f32x4*)&b0[nbase];
#pragma unroll
    for (int pt=0;pt<4;pt++) {
      int pix = pt*16 + col;
      half4 hv;
      hv[0] = (_Float16)gelu_f(acc[nt][pt][0] + bb[0]);
      hv[1] = (_Float16)gelu_f(acc[nt][pt][1] + bb[1]);
      hv[2] = (_Float16)gelu_f(acc[nt][pt][2] + bb[2]);
      hv[3] = (_Float16)gelu_f(acc[nt][pt][3] + bb[3]);
      *(half4*)&hA[pix*256 + (nbase ^ sw)] = hv;
    }
  }
  __syncthreads();

  // ---- 4 hidden layers: ping-pong hA <-> hB ----
  for (int L=0; L<4; L++) {
    const _Float16* hs = (L & 1) ? hB : hA;
    _Float16*       hd = (L & 1) ? hA : hB;
    const half8* AL = (const half8*)(Wth + L*65536);
#pragma unroll
    for (int nt=0;nt<2;nt++)
#pragma unroll
      for (int pt=0;pt<4;pt++) acc[nt][pt] = vzero;
#pragma unroll
    for (int ks=0; ks<8; ks++) {
      int k0 = ks*32 + koff;
      half8 aw[2], bx[4];
#pragma unroll
      for (int nt=0;nt<2;nt++)
        aw[nt] = AL[((wave*2+nt)*8 + ks)*64 + lane];
#pragma unroll
      for (int pt=0;pt<4;pt++)
        bx[pt] = *(const half8*)&hs[(pt*16+col)*256 + (k0 ^ sw)];
#pragma unroll
      for (int nt=0;nt<2;nt++)
#pragma unroll
        for (int pt=0;pt<4;pt++)
          acc[nt][pt] = __builtin_amdgcn_mfma_f32_16x16x32_f16(aw[nt], bx[pt], acc[nt][pt], 0,0,0);
    }
#pragma unroll
    for (int nt=0;nt<2;nt++) {
      int nbase = wave*32 + nt*16 + rbase;
      f32x4 bb = *(const f32x4*)&bh[L*HID + nbase];
#pragma unroll
      for (int pt=0;pt<4;pt++) {
        int pix = pt*16 + col;
        half4 hv;
        hv[0] = (_Float16)gelu_f(acc[nt][pt][0] + bb[0]);
        hv[1] = (_Float16)gelu_f(acc[nt][pt][1] + bb[1]);
        hv[2] = (_Float16)gelu_f(acc[nt][pt][2] + bb[2]);
        hv[3] = (_Float16)gelu_f(acc[nt][pt][3] + bb[3]);
        *(half4*)&hd[pix*256 + (nbase ^ sw)] = hv;
      }
    }
    __syncthreads();
  }

  // ---- head: Whd(A) x hA(B) -> 200 logits/pixel into kbuf[pix][208] ----
#pragma unroll
  for (int nt=0;nt<2;nt++)
#pragma unroll
    for (int pt=0;pt<4;pt++) acc[nt][pt] = vzero;
#pragma unroll
  for (int ks=0; ks<8; ks++) {
    int k0 = ks*32 + koff;
    half8 aw[2], bx[4];
#pragma unroll
    for (int nt=0;nt<2;nt++)
      aw[nt] = AH[((wave*2+nt)*8 + ks)*64 + lane];
#pragma unroll
    for (int pt=0;pt<4;pt++)
      bx[pt] = *(const half8*)&hA[(pt*16+col)*256 + (k0 ^ sw)];
#pragma unroll
    for (int nt=0;nt<2;nt++)
#pragma unroll
      for (int pt=0;pt<4;pt++)
        acc[nt][pt] = __builtin_amdgcn_mfma_f32_16x16x32_f16(aw[nt], bx[pt], acc[nt][pt], 0,0,0);
  }
#pragma unroll
  for (int nt=0;nt<2;nt++) {
    int jb = wave*32 + nt*16 + rbase;
    if (jb < 200) {
      const float* bp = (jb < 196) ? (kb + jb) : (gb + (jb - 196));
      f32x4 bb = *(const f32x4*)bp;
#pragma unroll
      for (int pt=0;pt<4;pt++) {
        int pix = pt*16 + col;
        half4 kv;
        kv[0] = (_Float16)(acc[nt][pt][0] + bb[0]);
        kv[1] = (_Float16)(acc[nt][pt][1] + bb[1]);
        kv[2] = (_Float16)(acc[nt][pt][2] + bb[2]);
        kv[3] = (_Float16)(acc[nt][pt][3] + bb[3]);
        *(half4*)&kbuf[pix*208 + jb] = kv;
      }
    }
  }
  __syncthreads();

  // ---- Phase E: split max/sum (8 threads/pixel), NO exp write-back; ----
  // ---- pass 2 recomputes exp from fp16 logits (round-6 numerics).   ----
  {
    int p = tid >> 3, q = tid & 7;
    int h = q & 3, part = q >> 2;
    int hx = hx0 + p;
    float lx = (hx+0.5f)*0.25f - 0.5f;
    int bxi = min(max((int)floorf(lx),0), WL-1);
    const _Float16* kp = &kbuf[p*208];
    // gate softmax (redundant on 8 threads)
    float g0=(float)kp[196], g1=(float)kp[197], g2=(float)kp[198], g3=(float)kp[199];
    float gm = fmaxf(fmaxf(g0,g1), fmaxf(g2,g3));
    g0=__expf(g0-gm); g1=__expf(g1-gm); g2=__expf(g2-gm); g3=__expf(g3-gm);
    float gs = __builtin_amdgcn_rcpf(g0+g1+g2+g3);
    float gate[4] = {g0*gs, g1*gs, g2*gs, g3*gs};
    // pass 1: head h, taps [part*25, part*25+cnt)
    const int t0 = part*25;
    const int cnt = part ? 24 : 25;
    float rv[25];
#pragma unroll
    for (int i=0;i<25;i++) rv[i] = (i<cnt) ? (float)kp[h*K2 + t0 + i] : -1e30f;
    float mh = rv[0];
#pragma unroll
    for (int i=1;i<25;i++) mh = fmaxf(mh, rv[i]);
    mh = fmaxf(mh, __shfl_xor(mh, 4));
    float sh = 0.f;
#pragma unroll
    for (int i=0;i<25;i++)
      if (i<cnt) sh += __expf(rv[i]-mh);
    sh += __shfl_xor(sh, 4);
    int base = lane & ~7;
    float m[4], gos[4];
#pragma unroll
    for (int hh=0; hh<4; hh++) {
      m[hh]  = __shfl(mh, base+hh);
      float sv = __shfl(sh, base+hh);
      gos[hh] = gate[hh]*__builtin_amdgcn_rcpf(sv);
    }
    // pass 2: recompute exps from logits (no fp16 quantization of weights)
    float r0=0.f, r1=0.f, r2=0.f;
    if (q < 7) {
      int dy = q-3;
      int ny = min(max(byi+dy,0),HL-1);
#pragma unroll
      for (int i=0;i<7;i++) {
        int t = q*7+i;
        int nx = min(max(bxi+i-3,0),WL-1);
        float wq = gos[0]*__expf((float)kp[t]-m[0]) + gos[1]*__expf((float)kp[K2+t]-m[1])
                 + gos[2]*__expf((float)kp[2*K2+t]-m[2]) + gos[3]*__expf((float)kp[3*K2+t]-m[3]);
        int o = ny*WL + nx;
        r0 += wq*lr[o]; r1 += wq*lr[LRPIX+o]; r2 += wq*lr[2*LRPIX+o];
      }
    }
#pragma unroll
    for (int msk=1; msk<8; msk<<=1) {
      r0 += __shfl_xor(r0, msk);
      r1 += __shfl_xor(r1, msk);
      r2 += __shfl_xor(r2, msk);
    }
    if (q == 0) {
      int n = n0 + p;
      res0[n] = r0; res0[NPIX+n] = r1; res0[2*NPIX+n] = r2;
    }
  }
}

// ------ refiner conv0: groups=3, 2ch -> 16ch, GELU; out NHWC [NPIX][48] -----
__global__ void rconv0(const float* __restrict__ lrup, const float* __restrict__ res0,
                       const float* __restrict__ w, const float* __restrict__ bias,
                       float* __restrict__ out) {
  __shared__ float wl[288];      // [tap][ic2][oc16]
  int tid = threadIdx.x;
  int g = blockIdx.y;
  for (int idx = tid; idx < 288; idx += 256) {
    int o = idx/18, r = idx - o*18, ic = r/9, tap = r - ic*9;
    wl[tap*32 + ic*16 + o] = w[((g*16+o)*2+ic)*9 + tap];
  }
  __syncthreads();
  int p = blockIdx.x*blockDim.x + tid;
  int y = p / WH, x = p % WH;
  float acc[16];
#pragma unroll
  for (int o=0;o<16;o++) acc[o] = bias[g*16+o];
#pragma unroll
  for (int ky=0;ky<3;ky++) {
    int yy = y+ky-1;
    if (yy<0||yy>=HH) continue;
#pragma unroll
    for (int kx=0;kx<3;kx++) {
      int xx = x+kx-1;
      if (xx<0||xx>=WH) continue;
      int o0 = yy*WH+xx, tap = ky*3+kx;
#pragma unroll
      for (int ic=0; ic<2; ic++) {
        float v = (ic==0 ? lrup : res0)[g*NPIX + o0];
        const f32x4* wb = (const f32x4*)&wl[tap*32 + ic*16];
#pragma unroll
        for (int ov=0; ov<4; ov++) {
          f32x4 wv = wb[ov];
#pragma unroll
          for (int oo=0; oo<4; oo++) acc[ov*4+oo] += v*wv[oo];
        }
      }
    }
  }
  float* dst = out + p*48 + g*16;
#pragma unroll
  for (int o=0;o<16;o++) dst[o] = gelu_f(acc[o]);
}

// ------ refiner conv1: groups=3, 16->16, GELU; NHWC [NPIX][48]; LDS w ------
__global__ void rconv1(const float* __restrict__ hr0, const float* __restrict__ w,
                       const float* __restrict__ bias, float* __restrict__ out) {
  __shared__ float wl[2304];     // [tap][ic16][oc16] 9.2 KB
  int tid = threadIdx.x;
  int g = blockIdx.y;
  const float* wsrc = w + g*2304;   // [16 oc][16 ic][9 tap]
#pragma unroll
  for (int i=0;i<9;i++) {
    int idx = tid + i*256;
    int o = idx/144, r = idx - o*144, ic = r/9, tap = r - ic*9;
    wl[tap*256 + ic*16 + o] = wsrc[idx];
  }
  __syncthreads();
  int p = blockIdx.x*blockDim.x + tid;
  int y = p / WH, x = p % WH;
  float acc[16];
#pragma unroll
  for (int o=0;o<16;o++) acc[o] = bias[g*16+o];
#pragma unroll
  for (int ky=0;ky<3;ky++) {
    int yy = y+ky-1;
    if (yy<0||yy>=HH) continue;
#pragma unroll
    for (int kx=0;kx<3;kx++) {
      int xx = x+kx-1;
      if (xx<0||xx>=WH) continue;
      const f32x4* src = (const f32x4*)&hr0[(yy*WH+xx)*48 + g*16];
      const float* wt = &wl[(ky*3+kx)*256];
#pragma unroll
      for (int icv=0; icv<4; icv++) {
        f32x4 v = src[icv];
#pragma unroll
        for (int j=0;j<4;j++) {
          const f32x4* wb = (const f32x4*)&wt[(icv*4+j)*16];
#pragma unroll
          for (int ov=0; ov<4; ov++) {
            f32x4 wv = wb[ov];
#pragma unroll
            for (int oo=0; oo<4; oo++) acc[ov*4+oo] += v[j]*wv[oo];
          }
        }
      }
    }
  }
  float* dst = out + p*48 + g*16;
#pragma unroll
  for (int o=0;o<16;o++) dst[o] = gelu_f(acc[o]);
}

// --------- refiner conv2 (16->1 per group) + sr + gray fusion + clip --------
__global__ void rconv2_fuse(const float* __restrict__ hr1, const float* __restrict__ lrup,
                            const float* __restrict__ res0, const float* __restrict__ w,
                            const float* __restrict__ bias, float* __restrict__ out) {
  __shared__ float wl[432];      // [tap][c][ic16]
  int tid = threadIdx.x;
  for (int idx = tid; idx < 432; idx += 256) {
    int c = idx/144, r = idx - c*144, ic = r/9, tap = r - ic*9;
    wl[tap*48 + c*16 + ic] = w[idx];
  }
  __syncthreads();
  int p = blockIdx.x*blockDim.x + tid;
  if (p >= NPIX) return;
  int y = p / WH, x = p % WH;
  float acc3[3];
#pragma unroll
  for (int c=0;c<3;c++) acc3[c] = bias[c];
#pragma unroll
  for (int ky=0;ky<3;ky++) {
    int yy=y+ky-1; if (yy<0||yy>=HH) continue;
#pragma unroll
    for (int kx=0;kx<3;kx++) {
      int xx=x+kx-1; if (xx<0||xx>=WH) continue;
      const f32x4* src = (const f32x4*)&hr1[(yy*WH+xx)*48];
      const float* wt = &wl[(ky*3+kx)*48];
#pragma unroll
      for (int c=0;c<3;c++) {
#pragma unroll
        for (int icv=0; icv<4; icv++) {
          f32x4 v = src[c*4 + icv];
          f32x4 wv = *(const f32x4*)&wt[c*16 + icv*4];
          acc3[c] += v[0]*wv[0] + v[1]*wv[1] + v[2]*wv[2] + v[3]*wv[3];
        }
      }
    }
  }
  float sr[3], lu[3];
#pragma unroll
  for (int c=0;c<3;c++) {
    float l = lrup[c*NPIX+p];
    lu[c]=l;
    float srv = l + res0[c*NPIX+p] + acc3[c];
    sr[c] = fminf(fmaxf(srv,0.f),1.f);
  }
  float delta = 0.2989f*(sr[0]-lu[0]) + 0.587f*(sr[1]-lu[1]) + 0.114f*(sr[2]-lu[2]);
#pragma unroll
  for (int c=0;c<3;c++)
    out[c*NPIX+p] = fminf(fmaxf(lu[c]+delta,0.f),1.f);
}

// ---------------------------------------------------------------------------
extern "C" void kernel_launch(void* const* d_in, const int* in_sizes, int n_in,
                              void* d_out, int out_size, void* d_ws, size_t ws_size,
                              hipStream_t stream) {
  const float* lr     = (const float*)d_in[0];
  const float* enc_w0 = (const float*)d_in[1];
  const float* enc_b0 = (const float*)d_in[2];
  const float* enc_wh = (const float*)d_in[3];
  const float* enc_bh = (const float*)d_in[4];
  const float* mlp_w0 = (const float*)d_in[5];
  const float* mlp_b0 = (const float*)d_in[6];
  const float* mlp_wh = (const float*)d_in[7];
  const float* mlp_bh = (const float*)d_in[8];
  const float* kern_w = (const float*)d_in[9];
  const float* kern_b = (const float*)d_in[10];
  const float* gate_w = (const float*)d_in[11];
  const float* gate_b = (const float*)d_in[12];
  const float* ref_w0 = (const float*)d_in[13];
  const float* ref_b0 = (const float*)d_in[14];
  const float* ref_w1 = (const float*)d_in[15];
  const float* ref_b1 = (const float*)d_in[16];
  const float* ref_w2 = (const float*)d_in[17];
  const float* ref_b2 = (const float*)d_in[18];
  float* out = (float*)d_out;
  float* ws = (float*)d_ws;

  float* f_a  = ws;                 // 409600 floats, NHWC [6400][64]
  float* f_b  = ws + 409600;        // 409600, NHWC
  float* lrup = ws + 819200;        // 307200, NCHW [3][NPIX]
  float* res0 = ws + 1126400;       // 307200, NCHW
  float* hr0  = ws + 1433600;       // 4915200, NHWC [NPIX][48]
  float* hr1  = ws + 6348800;       // 4915200, NHWC

  _Float16* Wt0 = (_Float16*)f_a;   // 360448 halfs = 704 KB in f_a region
  _Float16* Wth = Wt0 + 32768;
  _Float16* Whd = Wth + 4*65536;

  enc_conv0<<<dim3(25,8), 256, 0, stream>>>(lr, enc_w0, enc_b0, f_a);
  enc_convh<<<dim3(50,8), 128, 0, stream>>>(f_a, enc_wh + 0*36864, enc_bh + 0,   f_b);
  enc_convh<<<dim3(50,8), 128, 0, stream>>>(f_b, enc_wh + 1*36864, enc_bh + 64,  f_a);
  enc_convh<<<dim3(50,8), 128, 0, stream>>>(f_a, enc_wh + 2*36864, enc_bh + 128, f_b);

  bicubic_up<<<1200, 256, 0, stream>>>(lr, lrup);

  // f_a now dead -> build packed fp16 weights there
  prep_weights<<<1408, 256, 0, stream>>>(mlp_w0, mlp_wh, kern_w, gate_w, Wt0);

  pixel_mlp2<<<1600, PMT, 0, stream>>>(f_b, lr, Wt0, mlp_b0, Wth, mlp_bh,
                                       Whd, kern_b, gate_b, res0);

  rconv0<<<dim3(400,3), 256, 0, stream>>>(lrup, res0, ref_w0, ref_b0, hr0);
  rconv1<<<dim3(400,3), 256, 0, stream>>>(hr0, ref_w1, ref_b1, hr1);
  rconv2_fuse<<<400, 256, 0, stream>>>(hr1, lrup, res0, ref_w2, ref_b2, out);
}